// Round 1
// baseline (2359.610 us; speedup 1.0000x reference)
//
#include <hip/hip_runtime.h>

#define BB 64
#define TT 500
#define HH 128

typedef __attribute__((ext_vector_type(8))) short short8v;
typedef __attribute__((ext_vector_type(4))) short short4v;
typedef __attribute__((ext_vector_type(4))) float float4v;

__device__ __forceinline__ unsigned short f2bf(float f) {
  union { float f; unsigned u; } v; v.f = f;
  unsigned r = v.u + 0x7FFFu + ((v.u >> 16) & 1u);
  return (unsigned short)(r >> 16);
}
__device__ __forceinline__ float bf2f(unsigned short u) {
  union { unsigned u; float f; } v; v.u = ((unsigned)u) << 16;
  return v.f;
}
__device__ __forceinline__ float sigm(float x) {
  return __builtin_amdgcn_rcpf(1.f + __builtin_amdgcn_exp2f(-1.44269504088896341f * x));
}
__device__ __forceinline__ float tanh_f(float x) {
  return 1.f - 2.f * __builtin_amdgcn_rcpf(1.f + __builtin_amdgcn_exp2f(2.88539008177792682f * x));
}

// ---------------------------------------------------------------------------
// Phase 1: all token-parallel precompute.
// Per token: s_emb (sparse gather-avg), e_emb, a_emb -> X[384];
//   se_data / se_learning / e_learning -> Y[384];
//   gx[384] (GRU input gates, bf16), xgx[256] (gain|gate learning-side + bias, bf16),
//   wall[32] (f32), c1 = e_emb.Wp[256:]+bp, c2 = se_data.Wp1[256:]+bp1.
// Grid: 64 b * 32 chunks of 16 tokens, 256 threads.
// ---------------------------------------------------------------------------
__global__ __launch_bounds__(256) void phase1_k(
    const int* __restrict__ a_data, const int* __restrict__ e_data,
    const float* __restrict__ qm, const float* __restrict__ semb,
    const float* __restrict__ aemb, const float* __restrict__ eemb,
    const float* __restrict__ W1, const float* __restrict__ b1,
    const float* __restrict__ W2, const float* __restrict__ b2,
    const float* __restrict__ W3, const float* __restrict__ b3,
    const float* __restrict__ key, const float* __restrict__ Wih,
    const float* __restrict__ bih,
    const float* __restrict__ Wg, const float* __restrict__ bg,
    const float* __restrict__ Wgg, const float* __restrict__ bgg,
    const float* __restrict__ Wp, const float* __restrict__ bp,
    const float* __restrict__ Wp1, const float* __restrict__ bp1,
    unsigned short* __restrict__ gxb, unsigned short* __restrict__ xgx,
    float* __restrict__ wallb, float* __restrict__ c1b, float* __restrict__ c2b)
{
  __shared__ float X[16][388];   // stride 388 breaks bank-conflict on row accesses
  __shared__ float Y[16][388];
  const int tid = threadIdx.x;
  const int b = blockIdx.x >> 5;
  const int chunk = blockIdx.x & 31;
  const int t0 = chunk * 16;
  const int NT = (TT - t0 < 16) ? (TT - t0) : 16;

  // ---- stage 0: build X = [s_emb | e_emb | a_emb]
  {
    const int grp = tid >> 5;      // 0..7, 32 lanes per token
    const int l32 = tid & 31;
    const int h0 = l32 * 4;
    for (int tau = grp; tau < 16; tau += 8) {
      if (tau < NT) {
        const int tok = b * TT + t0 + tau;
        const int e = e_data[tok];
        const int a = a_data[tok];
        float4v acc = {0.f, 0.f, 0.f, 0.f};
        float cnt = 0.f;
        const float* qrow = qm + (size_t)e * 101;
        for (int s = 0; s < 101; ++s) {
          float q = qrow[s];
          if (q != 0.f) {
            float4v sv = *(const float4v*)(semb + s * HH + h0);
            acc += sv;
            cnt += 1.f;
          }
        }
        float inv = 1.f / fmaxf(cnt, 1.f);
        *(float4v*)(&X[tau][h0])       = acc * inv;
        *(float4v*)(&X[tau][128 + h0]) = *(const float4v*)(eemb + (size_t)e * HH + h0);
        *(float4v*)(&X[tau][256 + h0]) = *(const float4v*)(aemb + a * HH + h0);
      }
    }
  }
  __syncthreads();

  // ---- stage A: Y = [se_data | se_learning | e_learning]
  for (int it = 0; it < 24; ++it) {
    int idx = it * 256 + tid;      // 384 outputs * 16 tokens
    int og = idx >> 4, tau = idx & 15;
    if (tau >= NT) continue;
    const float* Wrow; const float* Xr; int len; float acc;
    if (og < 128)      { Wrow = W1 + og * 256;         Xr = &X[tau][0];   len = 256; acc = b1[og]; }
    else if (og < 256) { Wrow = W2 + (og - 128) * 384; Xr = &X[tau][0];   len = 384; acc = b2[og - 128]; }
    else               { Wrow = W3 + (og - 256) * 256; Xr = &X[tau][128]; len = 256; acc = b3[og - 256]; }
    for (int j = 0; j < len; j += 4) {
      float4v w = *(const float4v*)(Wrow + j);
      float4v x = *(const float4v*)(Xr + j);
      acc = fmaf(w[0], x[0], fmaf(w[1], x[1], fmaf(w[2], x[2], fmaf(w[3], x[3], acc))));
    }
    Y[tau][og] = fmaxf(acc, 0.f);
  }
  __syncthreads();

  // ---- stage B: gx (384), xgx (256), wall (32)
  for (int it = 0; it < 42; ++it) {
    int idx = it * 256 + tid;      // 672 outputs * 16 tokens
    int og = idx >> 4, tau = idx & 15;
    if (tau >= NT) continue;
    const int tok = b * TT + t0 + tau;
    if (og < 384) {
      const float* Wrow = Wih + og * 128;
      const float* Yr = &Y[tau][256];
      float acc = bih[og];
      for (int j = 0; j < 128; j += 4) {
        float4v w = *(const float4v*)(Wrow + j);
        float4v x = *(const float4v*)(Yr + j);
        acc = fmaf(w[0], x[0], fmaf(w[1], x[1], fmaf(w[2], x[2], fmaf(w[3], x[3], acc))));
      }
      gxb[(size_t)tok * 384 + og] = f2bf(acc);
    } else if (og < 640) {
      int o = og - 384;
      const float* Wrow = (o < 128) ? (Wg + o * 256 + 128) : (Wgg + (o - 128) * 256 + 128);
      float acc = (o < 128) ? bg[o] : bgg[o - 128];
      const float* Yr = &Y[tau][128];
      for (int j = 0; j < 128; j += 4) {
        float4v w = *(const float4v*)(Wrow + j);
        float4v x = *(const float4v*)(Yr + j);
        acc = fmaf(w[0], x[0], fmaf(w[1], x[1], fmaf(w[2], x[2], fmaf(w[3], x[3], acc))));
      }
      xgx[(size_t)tok * 256 + o] = f2bf(acc);
    } else {
      int k = og - 640;
      const float* Wrow = key + k * 128;
      const float* Yr = &Y[tau][0];
      float acc = 0.f;
      for (int j = 0; j < 128; j += 4) {
        float4v w = *(const float4v*)(Wrow + j);
        float4v x = *(const float4v*)(Yr + j);
        acc = fmaf(w[0], x[0], fmaf(w[1], x[1], fmaf(w[2], x[2], fmaf(w[3], x[3], acc))));
      }
      wallb[(size_t)tok * 32 + k] = acc;
    }
  }
  // ---- c1/c2 scalars
  if (tid < 32) {
    int tau = tid & 15, which = tid >> 4;
    if (tau < NT) {
      const int tok = b * TT + t0 + tau;
      const float* w = (which ? Wp1 : Wp) + 256;
      const float* xr = which ? &Y[tau][0] : &X[tau][128];
      float acc = which ? bp1[0] : bp[0];
      for (int j = 0; j < 128; ++j) acc = fmaf(w[j], xr[j], acc);
      (which ? c2b : c1b)[tok] = acc;
    }
  }
}

// ---------------------------------------------------------------------------
// Fused sequential-scan kernel. 128 blocks x 512 threads.
// blocks 0..63  : key-value memory scan for batch b (MFMA for h_pre @ WfA^T)
// blocks 64..127: GRU for batch b-64 (MFMA for Whh @ h, broadcast B-operand)
// ---------------------------------------------------------------------------
__global__ __launch_bounds__(512) void scan_k(
    const float* __restrict__ Wf, const float* __restrict__ bf_,
    const float* __restrict__ Wg, const float* __restrict__ Wgg,
    const float* __restrict__ Whh, const float* __restrict__ bhh,
    const float* __restrict__ h0v, const float* __restrict__ m0,
    const float* __restrict__ Wp, const float* __restrict__ Wp1,
    const unsigned short* __restrict__ gxb, const unsigned short* __restrict__ xgx,
    const float* __restrict__ wallb,
    float* __restrict__ hts, float* __restrict__ pA, float* __restrict__ pB)
{
  const int tid = threadIdx.x;
  const int w = tid >> 6;        // wave 0..7
  const int lane = tid & 63;
  const int c = lane & 15;
  const int qq = lane >> 4;

  if (blockIdx.x < 64) {
    // ================= memory scan =================
    const int b = blockIdx.x;
    __shared__ unsigned short h_bf[32 * 128];  // bf16 h_pre, +k rotation swizzle on 16B groups
    __shared__ float ht_f[128];
    __shared__ float gg[256];
    __shared__ float LGf[128];
    __shared__ float lgww[128];

    const int n0 = w * 16 + qq * 4;   // this lane's 4 n-columns (C-frag rows)

    // A-frags: WfA rows (n = w*16+c), K chunks of 32
    short8v afr[4];
#pragma unroll
    for (int ks = 0; ks < 4; ++ks) {
      const float* src = Wf + (w * 16 + c) * 256 + ks * 32 + qq * 8;
      short8v tv;
#pragma unroll
      for (int j = 0; j < 8; ++j) tv[j] = (short)f2bf(src[j]);
      afr[ks] = tv;
    }
    // gain/gate ht-side weights: thread (o = tid>>1, half)
    const int o = tid >> 1, half = tid & 1;
    float ggw[64];
    {
      const float* src = (o < 128) ? (Wg + o * 256 + half * 64)
                                   : (Wgg + (o - 128) * 256 + half * 64);
#pragma unroll
      for (int j = 0; j < 64; ++j) ggw[j] = src[j];
    }
    // lgw weights: thread (o2 = tid>>2, q4)
    const int o2 = tid >> 2, q4 = tid & 3;
    float wfb[32];
    {
      const float* src = Wf + o2 * 256 + 128 + q4 * 32;
#pragma unroll
      for (int j = 0; j < 32; ++j) wfb[j] = src[j];
    }
    const float bfv = bf_[o2];

    // init h = m0 (lane holds h[k][n0..n0+3] for k = c and 16+c)
    float hreg[2][4];
#pragma unroll
    for (int nt = 0; nt < 2; ++nt) {
      int k = nt * 16 + c;
      float4v m = *(const float4v*)(m0 + k * HH + n0);
      hreg[nt][0] = m[0]; hreg[nt][1] = m[1]; hreg[nt][2] = m[2]; hreg[nt][3] = m[3];
      int p = ((n0 >> 3) + k) & 15;
      int idxw = k * 128 + p * 8 + (n0 & 7);
      short4v pk;
#pragma unroll
      for (int r = 0; r < 4; ++r) pk[r] = (short)f2bf(hreg[nt][r]);
      *(short4v*)(h_bf + idxw) = pk;
    }
    // ht0 = sum_k wall[b][0][k] * m0[k]
    {
      const float* wl = wallb + (size_t)b * TT * 32;
      float wn0 = wl[c], wn1 = wl[16 + c];
      float4v htp;
#pragma unroll
      for (int r = 0; r < 4; ++r) htp[r] = wn0 * hreg[0][r] + wn1 * hreg[1][r];
#pragma unroll
      for (int m = 1; m < 16; m <<= 1) {
        htp[0] += __shfl_xor(htp[0], m, 64);
        htp[1] += __shfl_xor(htp[1], m, 64);
        htp[2] += __shfl_xor(htp[2], m, 64);
        htp[3] += __shfl_xor(htp[3], m, 64);
      }
      if (c == 0) *(float4v*)(ht_f + n0) = htp;
    }
    __syncthreads();

    for (int t = 0; t < TT - 1; ++t) {
      // prefetch attention weights (w_t, w_{t+1}) and x-side gain/gate logit
      const float* wl = wallb + ((size_t)b * TT + t) * 32;
      float wv0 = wl[c], wv1 = wl[16 + c], wn0 = wl[32 + c], wn1 = wl[48 + c];
      float xv = 0.f;
      if (half == 0) xv = bf2f(xgx[((size_t)b * TT + t) * 256 + o]);

      // MFMA: C'[n][k] = sum_h WfA[n][h] * h_pre[k][h]  (depends only on h_{t-1})
      float4v acc0 = {0.f, 0.f, 0.f, 0.f}, acc1 = {0.f, 0.f, 0.f, 0.f};
#pragma unroll
      for (int ks = 0; ks < 4; ++ks) {
        int g = ks * 4 + qq;
        int p0 = (g + c) & 15;
        int p1 = (g + 16 + c) & 15;
        short8v bv0 = *(short8v*)(h_bf + c * 128 + p0 * 8);
        short8v bv1 = *(short8v*)(h_bf + (16 + c) * 128 + p1 * 8);
        acc0 = __builtin_amdgcn_mfma_f32_16x16x32_bf16(afr[ks], bv0, acc0, 0, 0, 0);
        acc1 = __builtin_amdgcn_mfma_f32_16x16x32_bf16(afr[ks], bv1, acc1, 0, 0, 0);
      }

      // gain/gate ht-side matvec (VALU, overlaps MFMA)
      float gac = 0.f;
      const float* hp = ht_f + half * 64;
#pragma unroll
      for (int j = 0; j < 64; j += 4) {
        float4v hx = *(const float4v*)(hp + j);
        gac = fmaf(ggw[j], hx[0], fmaf(ggw[j + 1], hx[1],
              fmaf(ggw[j + 2], hx[2], fmaf(ggw[j + 3], hx[3], gac))));
      }
      gac += __shfl_xor(gac, 1, 64);
      if (half == 0) gg[o] = gac + xv;
      __syncthreads();

      if (tid < 128) LGf[tid] = tanh_f(gg[tid]) * sigm(gg[tid + 128]);
      __syncthreads();

      // lgw[n] = LG . WfB[n] + bf[n]
      float la = 0.f;
      const float* lp = LGf + q4 * 32;
#pragma unroll
      for (int j = 0; j < 32; j += 4) {
        float4v l4 = *(const float4v*)(lp + j);
        la = fmaf(wfb[j], l4[0], fmaf(wfb[j + 1], l4[1],
             fmaf(wfb[j + 2], l4[2], fmaf(wfb[j + 3], l4[3], la))));
      }
      la += __shfl_xor(la, 1, 64);
      la += __shfl_xor(la, 2, 64);
      if (q4 == 0) lgww[o2] = la + bfv;
      __syncthreads();

      // epilogue: gam, h update, ht = sum_k w_next[k] h[k]
      float4v lg4 = *(const float4v*)(LGf + n0);
      float4v lw4 = *(const float4v*)(lgww + n0);
      float4v htp = {0.f, 0.f, 0.f, 0.f};
#pragma unroll
      for (int nt = 0; nt < 2; ++nt) {
        float wvv = nt ? wv1 : wv0;
        float wnn = nt ? wn1 : wn0;
        float4v a = nt ? acc1 : acc0;
#pragma unroll
        for (int r = 0; r < 4; ++r) {
          float gam = sigm(a[r] + lw4[r]);
          float hn = gam * hreg[nt][r] + wvv * lg4[r];
          hreg[nt][r] = hn;
          htp[r] += wnn * hn;
        }
        int k = nt * 16 + c;
        int p = ((n0 >> 3) + k) & 15;
        int idxw = k * 128 + p * 8 + (n0 & 7);
        short4v pk;
#pragma unroll
        for (int r = 0; r < 4; ++r) pk[r] = (short)f2bf(hreg[nt][r]);
        *(short4v*)(h_bf + idxw) = pk;
      }
#pragma unroll
      for (int m = 1; m < 16; m <<= 1) {
        htp[0] += __shfl_xor(htp[0], m, 64);
        htp[1] += __shfl_xor(htp[1], m, 64);
        htp[2] += __shfl_xor(htp[2], m, 64);
        htp[3] += __shfl_xor(htp[3], m, 64);
      }
      if (c == 0) {
        *(float4v*)(ht_f + n0) = htp;
        *(float4v*)(hts + ((size_t)b * TT + t) * 128 + n0) = htp;
      }
      __syncthreads();
    }
  } else {
    // ================= GRU =================
    const int b = blockIdx.x - 64;
    __shared__ float gh_l[384];
    __shared__ unsigned short hbg[128];
    __shared__ float redA[2], redB[2];

    short8v wfr[3][4];
    float4v bfr[3];
#pragma unroll
    for (int i = 0; i < 3; ++i) {
      int Mt = w + i * 8;
#pragma unroll
      for (int ks = 0; ks < 4; ++ks) {
        const float* src = Whh + (Mt * 16 + c) * 128 + ks * 32 + qq * 8;
        short8v tv;
#pragma unroll
        for (int j = 0; j < 8; ++j) tv[j] = (short)f2bf(src[j]);
        wfr[i][ks] = tv;
      }
      bfr[i] = *(const float4v*)(bhh + Mt * 16 + qq * 4);
    }
    float hj = 0.f, wpo = 0.f, wp1o = 0.f;
    if (tid < 128) {
      hj = h0v[tid];
      hbg[tid] = f2bf(hj);
      wpo = Wp[tid];
      wp1o = Wp1[tid];
    }
    __syncthreads();

    for (int t = 0; t < TT - 1; ++t) {
      float gr = 0.f, gz = 0.f, gn = 0.f;
      if (tid < 128) {
        const unsigned short* gp = gxb + ((size_t)b * TT + t) * 384;
        gr = bf2f(gp[tid]);
        gz = bf2f(gp[128 + tid]);
        gn = bf2f(gp[256 + tid]);
      }
      short8v bfrg[4];
#pragma unroll
      for (int ks = 0; ks < 4; ++ks)
        bfrg[ks] = *(short8v*)(hbg + ks * 32 + qq * 8);  // broadcast B-operand
      float4v acc0 = bfr[0], acc1 = bfr[1], acc2 = bfr[2];
#pragma unroll
      for (int ks = 0; ks < 4; ++ks) {
        acc0 = __builtin_amdgcn_mfma_f32_16x16x32_bf16(wfr[0][ks], bfrg[ks], acc0, 0, 0, 0);
        acc1 = __builtin_amdgcn_mfma_f32_16x16x32_bf16(wfr[1][ks], bfrg[ks], acc1, 0, 0, 0);
        acc2 = __builtin_amdgcn_mfma_f32_16x16x32_bf16(wfr[2][ks], bfrg[ks], acc2, 0, 0, 0);
      }
      if (c == 0) {
        *(float4v*)(gh_l + (w + 0) * 16 + qq * 4) = acc0;
        *(float4v*)(gh_l + (w + 8) * 16 + qq * 4) = acc1;
        *(float4v*)(gh_l + (w + 16) * 16 + qq * 4) = acc2;
      }
      __syncthreads();
      if (tid < 128) {
        float r = sigm(gr + gh_l[tid]);
        float z = sigm(gz + gh_l[128 + tid]);
        float n = tanh_f(gn + r * gh_l[256 + tid]);
        hj = (1.f - z) * n + z * hj;
        float pa = hj * wpo, pb = hj * wp1o;
#pragma unroll
        for (int m = 1; m < 64; m <<= 1) {
          pa += __shfl_xor(pa, m, 64);
          pb += __shfl_xor(pb, m, 64);
        }
        if (lane == 0) { redA[w] = pa; redB[w] = pb; }
        hbg[tid] = f2bf(hj);
      }
      __syncthreads();
      if (tid == 0) {
        pA[(size_t)b * TT + t] = redA[0] + redA[1];
        pB[(size_t)b * TT + t] = redB[0] + redB[1];
      }
    }
  }
}

// ---------------------------------------------------------------------------
// Combine: pred[b,0]=0; pred[b,t+1] = sigm(pA+ht.Wp[128:256]+c1[t+1]) *
//                                     sigm(pB+ht.Wp1[128:256]+c2[t+1])
// ---------------------------------------------------------------------------
__global__ __launch_bounds__(256) void combine_k(
    const float* __restrict__ hts, const float* __restrict__ pA,
    const float* __restrict__ pB, const float* __restrict__ c1b,
    const float* __restrict__ c2b, const float* __restrict__ Wp,
    const float* __restrict__ Wp1, float* __restrict__ out)
{
  const int b = blockIdx.x;
  const int wv = threadIdx.x >> 6;
  const int lane = threadIdx.x & 63;
  const float w1 = Wp[128 + lane], w2 = Wp[192 + lane];
  const float v1 = Wp1[128 + lane], v2 = Wp1[192 + lane];
  if (threadIdx.x == 0) out[(size_t)b * TT] = 0.f;
  for (int tau = wv; tau < TT - 1; tau += 4) {
    const float* h = hts + ((size_t)b * TT + tau) * 128;
    float x1 = h[lane], x2 = h[64 + lane];
    float qa = x1 * w1 + x2 * w2;
    float qb = x1 * v1 + x2 * v2;
#pragma unroll
    for (int m = 1; m < 64; m <<= 1) {
      qa += __shfl_xor(qa, m, 64);
      qb += __shfl_xor(qb, m, 64);
    }
    if (lane == 0) {
      float res = sigm(pA[(size_t)b * TT + tau] + qa + c1b[(size_t)b * TT + tau + 1]);
      float res1 = sigm(pB[(size_t)b * TT + tau] + qb + c2b[(size_t)b * TT + tau + 1]);
      out[(size_t)b * TT + tau + 1] = res * res1;
    }
  }
}

// ---------------------------------------------------------------------------
extern "C" void kernel_launch(void* const* d_in, const int* in_sizes, int n_in,
                              void* d_out, int out_size, void* d_ws, size_t ws_size,
                              hipStream_t stream) {
  (void)in_sizes; (void)n_in; (void)out_size; (void)ws_size;
  const int* a_data = (const int*)d_in[1];
  const int* e_data = (const int*)d_in[2];
  const float* qm   = (const float*)d_in[4];
  const float* semb = (const float*)d_in[5];
  const float* aemb = (const float*)d_in[6];
  const float* eemb = (const float*)d_in[7];
  const float* W1 = (const float*)d_in[8];   const float* b1 = (const float*)d_in[9];
  const float* W2 = (const float*)d_in[10];  const float* b2 = (const float*)d_in[11];
  const float* W3 = (const float*)d_in[12];  const float* b3 = (const float*)d_in[13];
  const float* key = (const float*)d_in[14];
  const float* Wih = (const float*)d_in[15]; const float* Whh = (const float*)d_in[16];
  const float* bih = (const float*)d_in[17]; const float* bhh = (const float*)d_in[18];
  const float* Wg  = (const float*)d_in[19]; const float* bg  = (const float*)d_in[20];
  const float* Wgg = (const float*)d_in[21]; const float* bgg = (const float*)d_in[22];
  const float* Wf  = (const float*)d_in[23]; const float* bf_ = (const float*)d_in[24];
  const float* Wp  = (const float*)d_in[25]; const float* bp  = (const float*)d_in[26];
  const float* Wp1 = (const float*)d_in[27]; const float* bp1 = (const float*)d_in[28];
  const float* h0v = (const float*)d_in[29]; const float* m0  = (const float*)d_in[30];

  char* ws = (char*)d_ws;
  unsigned short* gxb = (unsigned short*)(ws + 0);          // 64*500*384 bf16
  unsigned short* xgx = (unsigned short*)(ws + 24576000);   // 64*500*256 bf16
  float* wallb = (float*)(ws + 40960000);                   // 64*500*32 f32
  float* hts   = (float*)(ws + 45056000);                   // 64*500*128 f32
  float* c1b   = (float*)(ws + 61440000);
  float* c2b   = (float*)(ws + 61568000);
  float* pA    = (float*)(ws + 61696000);
  float* pB    = (float*)(ws + 61824000);
  float* out = (float*)d_out;

  phase1_k<<<dim3(2048), dim3(256), 0, stream>>>(
      a_data, e_data, qm, semb, aemb, eemb, W1, b1, W2, b2, W3, b3,
      key, Wih, bih, Wg, bg, Wgg, bgg, Wp, bp, Wp1, bp1,
      gxb, xgx, wallb, c1b, c2b);
  scan_k<<<dim3(128), dim3(512), 0, stream>>>(
      Wf, bf_, Wg, Wgg, Whh, bhh, h0v, m0, Wp, Wp1,
      gxb, xgx, wallb, hts, pA, pB);
  combine_k<<<dim3(64), dim3(256), 0, stream>>>(
      hts, pA, pB, c1b, c2b, Wp, Wp1, out);
}

// Round 2
// 1430.989 us; speedup vs baseline: 1.6489x; 1.6489x over previous
//
#include <hip/hip_runtime.h>

#define TT 500
typedef __attribute__((ext_vector_type(8))) short short8v;
typedef __attribute__((ext_vector_type(4))) short short4v;
typedef __attribute__((ext_vector_type(4))) float float4v;
typedef unsigned short ushort;

__device__ __forceinline__ ushort f2bf(float f) {
  union { float f; unsigned u; } v; v.f = f;
  unsigned r = v.u + 0x7FFFu + ((v.u >> 16) & 1u);
  return (ushort)(r >> 16);
}
__device__ __forceinline__ float bf2f(ushort u) {
  union { unsigned u; float f; } v; v.u = ((unsigned)u) << 16;
  return v.f;
}
__device__ __forceinline__ float sigm(float x) {
  return __builtin_amdgcn_rcpf(1.f + __builtin_amdgcn_exp2f(-1.44269504088896341f * x));
}
__device__ __forceinline__ float tanh_f(float x) {
  return 1.f - 2.f * __builtin_amdgcn_rcpf(1.f + __builtin_amdgcn_exp2f(2.88539008177792682f * x));
}

// ---------------------------------------------------------------------------
// phase0: convert weights to bf16 once per launch.
// layout in wts: w1b[128x256] w2b[128x384] w3b[128x256] wihb[384x128]
//                keyb[32x128] wgb[256x128] (Wg/Wgg learning-halves)
// ---------------------------------------------------------------------------
__global__ __launch_bounds__(256) void conv_k(
    const float* __restrict__ W1, const float* __restrict__ W2,
    const float* __restrict__ W3, const float* __restrict__ Wih,
    const float* __restrict__ key, const float* __restrict__ Wg,
    const float* __restrict__ Wgg, ushort* __restrict__ wts)
{
  int idx = blockIdx.x * 256 + threadIdx.x;
  if (idx >= 200704) return;
  float v;
  if (idx < 32768)       v = W1[idx];
  else if (idx < 81920)  v = W2[idx - 32768];
  else if (idx < 114688) v = W3[idx - 81920];
  else if (idx < 163840) v = Wih[idx - 114688];
  else if (idx < 167936) v = key[idx - 163840];
  else {
    int j = idx - 167936, o = j >> 7, k = j & 127;
    v = (o < 128) ? Wg[o * 256 + 128 + k] : Wgg[(o - 128) * 256 + 128 + k];
  }
  wts[idx] = f2bf(v);
}

// ---------------------------------------------------------------------------
// phase1: MFMA token-parallel precompute. 2048 blocks x 256 thr, 16 tok/block.
// X=[s_emb|e_emb|a_emb] -> Y=[se_data|se_learning|e_learning] -> gx/xgx/wall/c1/c2
// frag convention (verified R1): A/B row on lane&15, k at (lane>>4)*8;
// D: row(A)= (lane>>4)*4+r, col(B)= lane&15.
// ---------------------------------------------------------------------------
#define XS 424   // X/Y row stride (shorts): 848B = 212 banks = 20 mod 32 -> 2-way max
#define SS 648   // staging row stride

__global__ __launch_bounds__(256, 2) void phase1_k(
    const int* __restrict__ a_data, const int* __restrict__ e_data,
    const float* __restrict__ qm, const float* __restrict__ semb,
    const float* __restrict__ aemb, const float* __restrict__ eemb,
    const float* __restrict__ b1, const float* __restrict__ b2,
    const float* __restrict__ b3, const float* __restrict__ bih,
    const float* __restrict__ bg, const float* __restrict__ bgg,
    const float* __restrict__ Wp, const float* __restrict__ bp,
    const float* __restrict__ Wp1, const float* __restrict__ bp1,
    const ushort* __restrict__ wts,
    ushort* __restrict__ gxb, ushort* __restrict__ xgx,
    float* __restrict__ wallb, float* __restrict__ c1b, float* __restrict__ c2b)
{
  __shared__ ushort Xl[16 * XS];
  __shared__ ushort Yl[16 * XS];
  __shared__ ushort St[16 * SS];
  const int tid = threadIdx.x;
  const int b = blockIdx.x >> 5, chunk = blockIdx.x & 31;
  const int t0 = chunk * 16;
  const int NT = (TT - t0 < 16) ? (TT - t0) : 16;
  const ushort* w1b  = wts;
  const ushort* w2b  = wts + 32768;
  const ushort* w3b  = wts + 81920;
  const ushort* wihb = wts + 114688;
  const ushort* keyb = wts + 163840;
  const ushort* wgb  = wts + 167936;

  // ---- stage 0: X (bf16, all 16 rows valid via clamp)
  {
    const int tok = tid >> 4, l16 = tid & 15;
    const int tsrc = (tok < NT) ? tok : (NT - 1);
    const int gt = b * TT + t0 + tsrc;
    const int e = e_data[gt], a = a_data[gt];
    const float* qrow = qm + (size_t)e * 101;
    const float* sbase = semb + l16 * 8;
    float4v acc0 = {0,0,0,0}, acc1 = {0,0,0,0};
    float cnt = 0.f;
    for (int s = 0; s < 101; ++s) {
      float q = qrow[s];
      if (q != 0.f) {
        acc0 += *(const float4v*)(sbase + s * 128);
        acc1 += *(const float4v*)(sbase + s * 128 + 4);
        cnt += 1.f;
      }
    }
    float inv = 1.f / fmaxf(cnt, 1.f);
    ushort* xr = Xl + tok * XS + l16 * 8;
#pragma unroll
    for (int r = 0; r < 4; ++r) { xr[r] = f2bf(acc0[r] * inv); xr[4 + r] = f2bf(acc1[r] * inv); }
    const float* ee = eemb + (size_t)e * 128 + l16 * 8;
    const float* ae = aemb + a * 128 + l16 * 8;
    ushort* xe = Xl + tok * XS + 128 + l16 * 8;
    ushort* xa = Xl + tok * XS + 256 + l16 * 8;
#pragma unroll
    for (int r = 0; r < 8; ++r) { xe[r] = f2bf(ee[r]); xa[r] = f2bf(ae[r]); }
  }
  __syncthreads();

  const int w = tid >> 6, l = tid & 63, jj = l & 15, seg = l >> 4;

  // ---- stage A: Y via MFMA
  short8v ax[12];
#pragma unroll
  for (int i = 0; i < 12; ++i)
    ax[i] = *(short8v*)(Xl + jj * XS + i * 32 + seg * 8);

  for (int T = w; T < 24; T += 4) {
    float4v d = {0,0,0,0};
    float bv;
    if (T < 8) {
      const ushort* Bp = w1b + (T * 16 + jj) * 256 + seg * 8;
      bv = b1[T * 16 + jj];
#pragma unroll
      for (int k = 0; k < 8; ++k)
        d = __builtin_amdgcn_mfma_f32_16x16x32_bf16(ax[k], *(const short8v*)(Bp + k * 32), d, 0, 0, 0);
    } else if (T < 16) {
      const ushort* Bp = w2b + ((T - 8) * 16 + jj) * 384 + seg * 8;
      bv = b2[(T - 8) * 16 + jj];
#pragma unroll
      for (int k = 0; k < 12; ++k)
        d = __builtin_amdgcn_mfma_f32_16x16x32_bf16(ax[k], *(const short8v*)(Bp + k * 32), d, 0, 0, 0);
    } else {
      const ushort* Bp = w3b + ((T - 16) * 16 + jj) * 256 + seg * 8;
      bv = b3[(T - 16) * 16 + jj];
#pragma unroll
      for (int k = 0; k < 8; ++k)
        d = __builtin_amdgcn_mfma_f32_16x16x32_bf16(ax[4 + k], *(const short8v*)(Bp + k * 32), d, 0, 0, 0);
    }
#pragma unroll
    for (int r = 0; r < 4; ++r) {
      float y = d[r] + bv;
      Yl[(seg * 4 + r) * XS + T * 16 + jj] = f2bf(y > 0.f ? y : 0.f);
    }
  }
  __syncthreads();

  // ---- stage B: gx(0..23) / xgx(24..39) / wall(40..41)
  short8v ay[12];
#pragma unroll
  for (int i = 0; i < 12; ++i)
    ay[i] = *(short8v*)(Yl + jj * XS + i * 32 + seg * 8);

  float4v ds[11];
  int nst = 0;
  for (int T = w; T < 42; T += 4, ++nst) {
    const ushort* Bp; int ai;
    if (T < 24)      { Bp = wihb + (T * 16 + jj) * 128 + seg * 8;        ai = 8; }
    else if (T < 40) { Bp = wgb  + ((T - 24) * 16 + jj) * 128 + seg * 8; ai = 4; }
    else             { Bp = keyb + ((T - 40) * 16 + jj) * 128 + seg * 8; ai = 0; }
    float4v d = {0,0,0,0};
#pragma unroll
    for (int k = 0; k < 4; ++k)
      d = __builtin_amdgcn_mfma_f32_16x16x32_bf16(ay[ai + k], *(const short8v*)(Bp + k * 32), d, 0, 0, 0);
    ds[nst] = d;
  }
  nst = 0;
  for (int T = w; T < 42; T += 4, ++nst) {
    float4v d = ds[nst];
    if (T < 40) {
      float bv = (T < 24) ? bih[T * 16 + jj]
               : (T < 32) ? bg[(T - 24) * 16 + jj] : bgg[(T - 32) * 16 + jj];
      int col = (T < 24) ? (T * 16 + jj) : (384 + (T - 24) * 16 + jj);
#pragma unroll
      for (int r = 0; r < 4; ++r)
        St[(seg * 4 + r) * SS + col] = f2bf(d[r] + bv);
    } else {
#pragma unroll
      for (int r = 0; r < 4; ++r) {
        int tok = seg * 4 + r;
        if (tok < NT)
          wallb[((size_t)(b * TT + t0 + tok)) * 32 + (T - 40) * 16 + jj] = d[r];
      }
    }
  }
  __syncthreads();

  // ---- coalesced copy-out + c1/c2
  {
    const int tok = tid >> 4, sg = tid & 15;
    if (tok < NT) {
      size_t gt = (size_t)b * TT + t0 + tok;
#pragma unroll
      for (int p = 0; p < 3; ++p)
        *(short8v*)(gxb + gt * 384 + sg * 24 + p * 8) = *(short8v*)(St + tok * SS + sg * 24 + p * 8);
#pragma unroll
      for (int p = 0; p < 2; ++p)
        *(short8v*)(xgx + gt * 256 + sg * 16 + p * 8) = *(short8v*)(St + tok * SS + 384 + sg * 16 + p * 8);
    }
  }
  if (tid < 32) {
    int tau = tid & 15, which = tid >> 4;
    if (tau < NT) {
      const ushort* xr = which ? (Yl + tau * XS) : (Xl + tau * XS + 128);
      const float* wv = (which ? Wp1 : Wp) + 256;
      float acc = which ? bp1[0] : bp[0];
      for (int j = 0; j < 128; ++j) acc = fmaf(wv[j], bf2f(xr[j]), acc);
      (which ? c2b : c1b)[b * TT + t0 + tau] = acc;
    }
  }
}

// ---------------------------------------------------------------------------
// Fused scans: blocks 0..63 memory scan, 64..127 GRU. 512 thr, 2 barriers/step,
// all global loads prefetched one step ahead.
// ---------------------------------------------------------------------------
__global__ __launch_bounds__(512, 2) void scan_k(
    const float* __restrict__ Wf, const float* __restrict__ bf_,
    const float* __restrict__ Wg, const float* __restrict__ Wgg,
    const float* __restrict__ Whh, const float* __restrict__ bhh,
    const float* __restrict__ h0v, const float* __restrict__ m0,
    const ushort* __restrict__ gxb, const ushort* __restrict__ xgx,
    const float* __restrict__ wallb,
    ushort* __restrict__ htsm, ushort* __restrict__ htsg)
{
  const int tid = threadIdx.x;
  const int w = tid >> 6, l = tid & 63, jj = l & 15, seg = l >> 4;

  if (blockIdx.x < 64) {
    // ================= memory scan =================
    const int b = blockIdx.x;
    __shared__ ushort h_bf[32 * 128];  // bf16 h_pre, 16B-rotation swizzle
    __shared__ float ht_f[128];
    __shared__ float LGf[128];

    const int o = w * 16 + jj;        // P1/P2 output row; also MFMA A row
    const int n0 = w * 16 + seg * 4;  // this lane's 4 C-frag columns

    // A-frags: WfA rows
    short8v afr[4];
#pragma unroll
    for (int ks = 0; ks < 4; ++ks) {
      const float* src = Wf + o * 256 + ks * 32 + seg * 8;
      short8v tv;
#pragma unroll
      for (int j = 0; j < 8; ++j) tv[j] = (short)f2bf(src[j]);
      afr[ks] = tv;
    }
    // gain/gate ht-side weights (fp32), lgw weights
    float wgr[32], wggr[32], wfbr[32];
#pragma unroll
    for (int i = 0; i < 32; ++i) {
      wgr[i]  = Wg[o * 256 + seg * 32 + i];
      wggr[i] = Wgg[o * 256 + seg * 32 + i];
      wfbr[i] = Wf[o * 256 + 128 + seg * 32 + i];
    }
    const float bfv = bf_[o];

    // init h = m0
    float hreg[2][4];
#pragma unroll
    for (int nt = 0; nt < 2; ++nt) {
      int k = nt * 16 + jj;
      float4v m = *(const float4v*)(m0 + k * 128 + n0);
#pragma unroll
      for (int r = 0; r < 4; ++r) hreg[nt][r] = m[r];
      int p = ((n0 >> 3) + k) & 15;
      short4v pk;
#pragma unroll
      for (int r = 0; r < 4; ++r) pk[r] = (short)f2bf(hreg[nt][r]);
      *(short4v*)(h_bf + k * 128 + p * 8 + (n0 & 7)) = pk;
    }
    const float* wl = wallb + (size_t)b * TT * 32;
    const ushort* xgp = xgx + (size_t)b * TT * 256;
    float wv0 = wl[jj], wv1 = wl[16 + jj];           // w_0
    float wn0 = wl[32 + jj], wn1 = wl[48 + jj];      // w_1
    float xcur = (seg < 2) ? bf2f(xgp[seg * 128 + o]) : 0.f;
    // ht0
    {
      float4v htp;
#pragma unroll
      for (int r = 0; r < 4; ++r) htp[r] = wv0 * hreg[0][r] + wv1 * hreg[1][r];
#pragma unroll
      for (int m = 1; m < 16; m <<= 1) {
        htp[0] += __shfl_xor(htp[0], m, 64); htp[1] += __shfl_xor(htp[1], m, 64);
        htp[2] += __shfl_xor(htp[2], m, 64); htp[3] += __shfl_xor(htp[3], m, 64);
      }
      if (jj == 0) *(float4v*)(ht_f + n0) = htp;
    }
    __syncthreads();

    for (int t = 0; t < TT - 1; ++t) {
      // ---- prefetch step t+1 / t+2 (consumed next iteration)
      int tn = (t + 2 < TT - 1) ? (t + 2) : (TT - 1);
      float wf0 = wl[tn * 32 + jj], wf1 = wl[tn * 32 + 16 + jj];
      float xnext = (seg < 2) ? bf2f(xgp[(size_t)(t + 1) * 256 + seg * 128 + o]) : 0.f;

      // ---- MFMA: bigC[k][n] = h_pre[k] . WfA[n]  (off-chain, matrix pipe)
      float4v acc0 = {0,0,0,0}, acc1 = {0,0,0,0};
#pragma unroll
      for (int ks = 0; ks < 4; ++ks) {
        int g = ks * 4 + seg;
        int p0 = (g + jj) & 15;
        int p1 = (g + 16 + jj) & 15;
        short8v bv0 = *(short8v*)(h_bf + jj * 128 + p0 * 8);
        short8v bv1 = *(short8v*)(h_bf + (16 + jj) * 128 + p1 * 8);
        acc0 = __builtin_amdgcn_mfma_f32_16x16x32_bf16(afr[ks], bv0, acc0, 0, 0, 0);
        acc1 = __builtin_amdgcn_mfma_f32_16x16x32_bf16(afr[ks], bv1, acc1, 0, 0, 0);
      }

      // ---- P1: gain/gate logits (4 lanes per output), LG
      float ga = (seg == 0) ? xcur : 0.f;
      float gb = (seg == 1) ? xcur : 0.f;
#pragma unroll
      for (int i = 0; i < 32; i += 4) {
        float4v hx = *(const float4v*)(ht_f + seg * 32 + i);
        ga = fmaf(wgr[i], hx[0], fmaf(wgr[i+1], hx[1], fmaf(wgr[i+2], hx[2], fmaf(wgr[i+3], hx[3], ga))));
        gb = fmaf(wggr[i], hx[0], fmaf(wggr[i+1], hx[1], fmaf(wggr[i+2], hx[2], fmaf(wggr[i+3], hx[3], gb))));
      }
      ga += __shfl_xor(ga, 16, 64); ga += __shfl_xor(ga, 32, 64);
      gb += __shfl_xor(gb, 16, 64); gb += __shfl_xor(gb, 32, 64);
      float LG = tanh_f(ga) * sigm(gb);
      if (seg == 0) LGf[o] = LG;
      __syncthreads();  // B1

      // ---- P2: lgw + epilogue
      float la = 0.f;
#pragma unroll
      for (int i = 0; i < 32; i += 4) {
        float4v l4 = *(const float4v*)(LGf + seg * 32 + i);
        la = fmaf(wfbr[i], l4[0], fmaf(wfbr[i+1], l4[1], fmaf(wfbr[i+2], l4[2], fmaf(wfbr[i+3], l4[3], la))));
      }
      la += __shfl_xor(la, 16, 64); la += __shfl_xor(la, 32, 64);
      la += bfv;
      float lw[4];
#pragma unroll
      for (int r = 0; r < 4; ++r)
        lw[r] = __shfl(la, (l & 48) + seg * 4 + r, 64);
      float4v lg4 = *(const float4v*)(LGf + n0);

      float4v htp = {0,0,0,0};
#pragma unroll
      for (int nt = 0; nt < 2; ++nt) {
        float wvv = nt ? wv1 : wv0;
        float wnn = nt ? wn1 : wn0;
        float4v a = nt ? acc1 : acc0;
#pragma unroll
        for (int r = 0; r < 4; ++r) {
          float gam = sigm(a[r] + lw[r]);
          float hn = fmaf(gam, hreg[nt][r], wvv * lg4[r]);
          hreg[nt][r] = hn;
          htp[r] = fmaf(wnn, hn, htp[r]);
        }
        int k = nt * 16 + jj;
        int p = ((n0 >> 3) + k) & 15;
        short4v pk;
#pragma unroll
        for (int r = 0; r < 4; ++r) pk[r] = (short)f2bf(hreg[nt][r]);
        *(short4v*)(h_bf + k * 128 + p * 8 + (n0 & 7)) = pk;
      }
#pragma unroll
      for (int m = 1; m < 16; m <<= 1) {
        htp[0] += __shfl_xor(htp[0], m, 64); htp[1] += __shfl_xor(htp[1], m, 64);
        htp[2] += __shfl_xor(htp[2], m, 64); htp[3] += __shfl_xor(htp[3], m, 64);
      }
      if (jj == 0) {
        *(float4v*)(ht_f + n0) = htp;
        short4v hp;
#pragma unroll
        for (int r = 0; r < 4; ++r) hp[r] = (short)f2bf(htp[r]);
        *(short4v*)(htsm + ((size_t)b * TT + t) * 128 + n0) = hp;
      }
      wv0 = wn0; wv1 = wn1; wn0 = wf0; wn1 = wf1; xcur = xnext;
      __syncthreads();  // B2
    }
  } else {
    // ================= GRU =================
    const int b = blockIdx.x - 64;
    __shared__ float gh_l[384];
    __shared__ ushort hbg[128];

    short8v wfr[3][4];
    float4v bfr[3];
#pragma unroll
    for (int i = 0; i < 3; ++i) {
      int Mt = w + i * 8;
#pragma unroll
      for (int ks = 0; ks < 4; ++ks) {
        const float* src = Whh + (Mt * 16 + jj) * 128 + ks * 32 + seg * 8;
        short8v tv;
#pragma unroll
        for (int j = 0; j < 8; ++j) tv[j] = (short)f2bf(src[j]);
        wfr[i][ks] = tv;
      }
      bfr[i] = *(const float4v*)(bhh + Mt * 16 + seg * 4);
    }
    const ushort* gpb = gxb + (size_t)b * TT * 384;
    float hj = 0.f, g0 = 0.f, g1 = 0.f, g2 = 0.f;
    if (tid < 128) {
      hj = h0v[tid];
      hbg[tid] = f2bf(hj);
      g0 = bf2f(gpb[tid]); g1 = bf2f(gpb[128 + tid]); g2 = bf2f(gpb[256 + tid]);
    }
    __syncthreads();

    for (int t = 0; t < TT - 1; ++t) {
      ushort np0 = 0, np1 = 0, np2 = 0;
      if (tid < 128) {  // prefetch t+1
        const ushort* gn = gpb + (size_t)(t + 1) * 384;
        np0 = gn[tid]; np1 = gn[128 + tid]; np2 = gn[256 + tid];
      }
      short8v bfrg[4];
#pragma unroll
      for (int ks = 0; ks < 4; ++ks)
        bfrg[ks] = *(short8v*)(hbg + ks * 32 + seg * 8);
      float4v acc0 = bfr[0], acc1 = bfr[1], acc2 = bfr[2];
#pragma unroll
      for (int ks = 0; ks < 4; ++ks) {
        acc0 = __builtin_amdgcn_mfma_f32_16x16x32_bf16(wfr[0][ks], bfrg[ks], acc0, 0, 0, 0);
        acc1 = __builtin_amdgcn_mfma_f32_16x16x32_bf16(wfr[1][ks], bfrg[ks], acc1, 0, 0, 0);
        acc2 = __builtin_amdgcn_mfma_f32_16x16x32_bf16(wfr[2][ks], bfrg[ks], acc2, 0, 0, 0);
      }
      if (jj == 0) {
        *(float4v*)(gh_l + (w + 0) * 16 + seg * 4) = acc0;
        *(float4v*)(gh_l + (w + 8) * 16 + seg * 4) = acc1;
        *(float4v*)(gh_l + (w + 16) * 16 + seg * 4) = acc2;
      }
      __syncthreads();
      if (tid < 128) {
        float r = sigm(g0 + gh_l[tid]);
        float z = sigm(g1 + gh_l[128 + tid]);
        float n = tanh_f(g2 + r * gh_l[256 + tid]);
        hj = fmaf(1.f - z, n, z * hj);
        hbg[tid] = f2bf(hj);
        htsg[((size_t)b * TT + t) * 128 + tid] = f2bf(hj);
        g0 = bf2f(np0); g1 = bf2f(np1); g2 = bf2f(np2);
      }
      __syncthreads();
    }
  }
}

// ---------------------------------------------------------------------------
// combine: out[b,t+1] = sigm(hg.Wp[0:128]+hm.Wp[128:256]+c1[t+1]) *
//                       sigm(hg.Wp1[0:128]+hm.Wp1[128:256]+c2[t+1])
// ---------------------------------------------------------------------------
__global__ __launch_bounds__(256) void combine_k(
    const ushort* __restrict__ htsg, const ushort* __restrict__ htsm,
    const float* __restrict__ c1b, const float* __restrict__ c2b,
    const float* __restrict__ Wp, const float* __restrict__ Wp1,
    float* __restrict__ out)
{
  const int b = blockIdx.x;
  const int wv = threadIdx.x >> 6;
  const int lane = threadIdx.x & 63;
  const float w0 = Wp[lane], w1 = Wp[64 + lane], w2 = Wp[128 + lane], w3 = Wp[192 + lane];
  const float v0 = Wp1[lane], v1 = Wp1[64 + lane], v2 = Wp1[128 + lane], v3 = Wp1[192 + lane];
  if (threadIdx.x == 0) out[(size_t)b * TT] = 0.f;
  for (int tau = wv; tau < TT - 1; tau += 4) {
    size_t base = ((size_t)b * TT + tau) * 128;
    float hg0 = bf2f(htsg[base + lane]), hg1 = bf2f(htsg[base + 64 + lane]);
    float hm0 = bf2f(htsm[base + lane]), hm1 = bf2f(htsm[base + 64 + lane]);
    float qa = hg0 * w0 + hg1 * w1 + hm0 * w2 + hm1 * w3;
    float qb = hg0 * v0 + hg1 * v1 + hm0 * v2 + hm1 * v3;
#pragma unroll
    for (int m = 1; m < 64; m <<= 1) {
      qa += __shfl_xor(qa, m, 64);
      qb += __shfl_xor(qb, m, 64);
    }
    if (lane == 0) {
      size_t idx = (size_t)b * TT + tau + 1;
      out[idx] = sigm(qa + c1b[idx]) * sigm(qb + c2b[idx]);
    }
  }
}

// ---------------------------------------------------------------------------
extern "C" void kernel_launch(void* const* d_in, const int* in_sizes, int n_in,
                              void* d_out, int out_size, void* d_ws, size_t ws_size,
                              hipStream_t stream) {
  (void)in_sizes; (void)n_in; (void)out_size; (void)ws_size;
  const int* a_data = (const int*)d_in[1];
  const int* e_data = (const int*)d_in[2];
  const float* qm   = (const float*)d_in[4];
  const float* semb = (const float*)d_in[5];
  const float* aemb = (const float*)d_in[6];
  const float* eemb = (const float*)d_in[7];
  const float* W1 = (const float*)d_in[8];   const float* b1 = (const float*)d_in[9];
  const float* W2 = (const float*)d_in[10];  const float* b2 = (const float*)d_in[11];
  const float* W3 = (const float*)d_in[12];  const float* b3 = (const float*)d_in[13];
  const float* key = (const float*)d_in[14];
  const float* Wih = (const float*)d_in[15]; const float* Whh = (const float*)d_in[16];
  const float* bih = (const float*)d_in[17]; const float* bhh = (const float*)d_in[18];
  const float* Wg  = (const float*)d_in[19]; const float* bg  = (const float*)d_in[20];
  const float* Wgg = (const float*)d_in[21]; const float* bgg = (const float*)d_in[22];
  const float* Wf  = (const float*)d_in[23]; const float* bf_ = (const float*)d_in[24];
  const float* Wp  = (const float*)d_in[25]; const float* bp  = (const float*)d_in[26];
  const float* Wp1 = (const float*)d_in[27]; const float* bp1 = (const float*)d_in[28];
  const float* h0v = (const float*)d_in[29]; const float* m0  = (const float*)d_in[30];

  char* ws = (char*)d_ws;
  ushort* gxb  = (ushort*)(ws + 0);            // 64*500*384 bf16 = 24,576,000
  ushort* xgx  = (ushort*)(ws + 24576000);     // 64*500*256 bf16 = 16,384,000
  float* wallb = (float*)(ws + 40960000);      // 64*500*32 f32   =  4,096,000
  ushort* htsm = (ushort*)(ws + 45056000);     // 64*500*128 bf16 =  8,192,000
  ushort* htsg = (ushort*)(ws + 53248000);     // 64*500*128 bf16 =  8,192,000
  float* c1b   = (float*)(ws + 61440000);      // 128,000
  float* c2b   = (float*)(ws + 61568000);      // 128,000
  ushort* wts  = (ushort*)(ws + 61696000);     // 200,704 bf16 = 401,408
  float* out = (float*)d_out;

  conv_k<<<dim3(784), dim3(256), 0, stream>>>(W1, W2, W3, Wih, key, Wg, Wgg, wts);
  phase1_k<<<dim3(2048), dim3(256), 0, stream>>>(
      a_data, e_data, qm, semb, aemb, eemb, b1, b2, b3, bih, bg, bgg,
      Wp, bp, Wp1, bp1, wts, gxb, xgx, wallb, c1b, c2b);
  scan_k<<<dim3(128), dim3(512), 0, stream>>>(
      Wf, bf_, Wg, Wgg, Whh, bhh, h0v, m0, gxb, xgx, wallb, htsm, htsg);
  combine_k<<<dim3(64), dim3(256), 0, stream>>>(
      htsg, htsm, c1b, c2b, Wp, Wp1, out);
}

// Round 4
// 1275.561 us; speedup vs baseline: 1.8499x; 1.1219x over previous
//
#include <hip/hip_runtime.h>

#define TT 500
typedef __attribute__((ext_vector_type(8))) short short8v;
typedef __attribute__((ext_vector_type(4))) short short4v;
typedef __attribute__((ext_vector_type(4))) float float4v;
typedef unsigned short ushort;

__device__ __forceinline__ ushort f2bf(float f) {
  union { float f; unsigned u; } v; v.f = f;
  unsigned r = v.u + 0x7FFFu + ((v.u >> 16) & 1u);
  return (ushort)(r >> 16);
}
__device__ __forceinline__ float bf2f(ushort u) {
  union { unsigned u; float f; } v; v.u = ((unsigned)u) << 16;
  return v.f;
}
__device__ __forceinline__ float sigm(float x) {
  return __builtin_amdgcn_rcpf(1.f + __builtin_amdgcn_exp2f(-1.44269504088896341f * x));
}
__device__ __forceinline__ float tanh_f(float x) {
  return 1.f - 2.f * __builtin_amdgcn_rcpf(1.f + __builtin_amdgcn_exp2f(2.88539008177792682f * x));
}
// LDS-only barrier: does NOT drain vmcnt -> global prefetches stay in flight.
__device__ __forceinline__ void bar_lds() {
  asm volatile("s_waitcnt lgkmcnt(0)\ns_barrier" ::: "memory");
}
// DPP cross-lane adds (VALU pipe, no LDS). ctrl must be a compile-time const.
template <int CTRL>
__device__ __forceinline__ float dppadd(float v) {
  int a = __builtin_amdgcn_update_dpp(0, __builtin_bit_cast(int, v), CTRL, 0xF, 0xF, true);
  return v + __builtin_bit_cast(float, a);
}
__device__ __forceinline__ float qsum4(float v) {   // sum over quad (lane&3)
  v = dppadd<0xB1>(v);   // quad_perm [1,0,3,2]
  v = dppadd<0x4E>(v);   // quad_perm [2,3,0,1]
  return v;
}
__device__ __forceinline__ float rsum16(float v) {  // sum over 16-lane row
  v = dppadd<0xB1>(v);
  v = dppadd<0x4E>(v);
  v = dppadd<0x141>(v);  // row_half_mirror
  v = dppadd<0x140>(v);  // row_mirror
  return v;
}

// ---------------------------------------------------------------------------
// phase0: weights -> bf16
// ---------------------------------------------------------------------------
__global__ __launch_bounds__(256) void conv_k(
    const float* __restrict__ W1, const float* __restrict__ W2,
    const float* __restrict__ W3, const float* __restrict__ Wih,
    const float* __restrict__ key, const float* __restrict__ Wg,
    const float* __restrict__ Wgg, ushort* __restrict__ wts)
{
  int idx = blockIdx.x * 256 + threadIdx.x;
  if (idx >= 200704) return;
  float v;
  if (idx < 32768)       v = W1[idx];
  else if (idx < 81920)  v = W2[idx - 32768];
  else if (idx < 114688) v = W3[idx - 81920];
  else if (idx < 163840) v = Wih[idx - 114688];
  else if (idx < 167936) v = key[idx - 163840];
  else {
    int j = idx - 167936, o = j >> 7, k = j & 127;
    v = (o < 128) ? Wg[o * 256 + 128 + k] : Wgg[(o - 128) * 256 + 128 + k];
  }
  wts[idx] = f2bf(v);
}

// ---------------------------------------------------------------------------
// phase1: token-parallel precompute (MFMA GEMMs + ballot-compressed gather)
// ---------------------------------------------------------------------------
#define XS 424
#define SS 648

__global__ __launch_bounds__(256, 2) void phase1_k(
    const int* __restrict__ a_data, const int* __restrict__ e_data,
    const float* __restrict__ qm, const float* __restrict__ semb,
    const float* __restrict__ aemb, const float* __restrict__ eemb,
    const float* __restrict__ b1, const float* __restrict__ b2,
    const float* __restrict__ b3, const float* __restrict__ bih,
    const float* __restrict__ bg, const float* __restrict__ bgg,
    const float* __restrict__ Wp, const float* __restrict__ bp,
    const float* __restrict__ Wp1, const float* __restrict__ bp1,
    const ushort* __restrict__ wts,
    ushort* __restrict__ gxb, ushort* __restrict__ xgx,
    float* __restrict__ wallb, float* __restrict__ c1b, float* __restrict__ c2b)
{
  __shared__ ushort Xl[16 * XS];
  __shared__ ushort Yl[16 * XS];
  __shared__ ushort St[16 * SS];
  const int tid = threadIdx.x;
  const int b = blockIdx.x >> 5, chunk = blockIdx.x & 31;
  const int t0 = chunk * 16;
  const int NT = (TT - t0 < 16) ? (TT - t0) : 16;
  const ushort* w1b  = wts;
  const ushort* w2b  = wts + 32768;
  const ushort* w3b  = wts + 81920;
  const ushort* wihb = wts + 114688;
  const ushort* keyb = wts + 163840;
  const ushort* wgb  = wts + 167936;

  // ---- stage 0: X via ballot-compressed sparse gather
  {
    const int tok = tid >> 4, l16 = tid & 15;
    const int tsrc = (tok < NT) ? tok : (NT - 1);
    const int gt = b * TT + t0 + tsrc;
    const int e = e_data[gt], a = a_data[gt];
    const float* qrow = qm + (size_t)e * 101;
    float qv[7];
#pragma unroll
    for (int i = 0; i < 7; ++i) {
      int s = l16 + 16 * i;
      qv[i] = (s < 101) ? qrow[s] : 0.f;
    }
    const float* sbase = semb + l16 * 8;
    float4v acc0 = {0,0,0,0}, acc1 = {0,0,0,0};
    float cnt = 0.f;
#pragma unroll
    for (int i = 0; i < 7; ++i) {
      unsigned long long bal = __ballot(qv[i] != 0.f);
      unsigned m = (unsigned)((bal >> (tid & 48)) & 0xFFFFull);
      cnt += (float)__popc(m);
      while (m) {
        int s = 16 * i + __builtin_ctz(m);
        m &= m - 1;
        acc0 += *(const float4v*)(sbase + s * 128);
        acc1 += *(const float4v*)(sbase + s * 128 + 4);
      }
    }
    float inv = 1.f / fmaxf(cnt, 1.f);
    ushort* xr = Xl + tok * XS + l16 * 8;
#pragma unroll
    for (int r = 0; r < 4; ++r) { xr[r] = f2bf(acc0[r] * inv); xr[4 + r] = f2bf(acc1[r] * inv); }
    const float* ee = eemb + (size_t)e * 128 + l16 * 8;
    const float* ae = aemb + a * 128 + l16 * 8;
    ushort* xe = Xl + tok * XS + 128 + l16 * 8;
    ushort* xa = Xl + tok * XS + 256 + l16 * 8;
#pragma unroll
    for (int r = 0; r < 8; ++r) { xe[r] = f2bf(ee[r]); xa[r] = f2bf(ae[r]); }
  }
  __syncthreads();

  const int w = tid >> 6, l = tid & 63, jj = l & 15, seg = l >> 4;

  // ---- stage A: Y via MFMA
  short8v ax[12];
#pragma unroll
  for (int i = 0; i < 12; ++i)
    ax[i] = *(short8v*)(Xl + jj * XS + i * 32 + seg * 8);

  for (int T = w; T < 24; T += 4) {
    float4v d = {0,0,0,0};
    float bv;
    if (T < 8) {
      const ushort* Bp = w1b + (T * 16 + jj) * 256 + seg * 8;
      bv = b1[T * 16 + jj];
#pragma unroll
      for (int k = 0; k < 8; ++k)
        d = __builtin_amdgcn_mfma_f32_16x16x32_bf16(ax[k], *(const short8v*)(Bp + k * 32), d, 0, 0, 0);
    } else if (T < 16) {
      const ushort* Bp = w2b + ((T - 8) * 16 + jj) * 384 + seg * 8;
      bv = b2[(T - 8) * 16 + jj];
#pragma unroll
      for (int k = 0; k < 12; ++k)
        d = __builtin_amdgcn_mfma_f32_16x16x32_bf16(ax[k], *(const short8v*)(Bp + k * 32), d, 0, 0, 0);
    } else {
      const ushort* Bp = w3b + ((T - 16) * 16 + jj) * 256 + seg * 8;
      bv = b3[(T - 16) * 16 + jj];
#pragma unroll
      for (int k = 0; k < 8; ++k)
        d = __builtin_amdgcn_mfma_f32_16x16x32_bf16(ax[4 + k], *(const short8v*)(Bp + k * 32), d, 0, 0, 0);
    }
#pragma unroll
    for (int r = 0; r < 4; ++r) {
      float y = d[r] + bv;
      Yl[(seg * 4 + r) * XS + T * 16 + jj] = f2bf(y > 0.f ? y : 0.f);
    }
  }
  __syncthreads();

  // ---- stage B: gx / xgx / wall
  short8v ay[12];
#pragma unroll
  for (int i = 0; i < 12; ++i)
    ay[i] = *(short8v*)(Yl + jj * XS + i * 32 + seg * 8);

  float4v ds[11];
  int nst = 0;
  for (int T = w; T < 42; T += 4, ++nst) {
    const ushort* Bp; int ai;
    if (T < 24)      { Bp = wihb + (T * 16 + jj) * 128 + seg * 8;        ai = 8; }
    else if (T < 40) { Bp = wgb  + ((T - 24) * 16 + jj) * 128 + seg * 8; ai = 4; }
    else             { Bp = keyb + ((T - 40) * 16 + jj) * 128 + seg * 8; ai = 0; }
    float4v d = {0,0,0,0};
#pragma unroll
    for (int k = 0; k < 4; ++k)
      d = __builtin_amdgcn_mfma_f32_16x16x32_bf16(ay[ai + k], *(const short8v*)(Bp + k * 32), d, 0, 0, 0);
    ds[nst] = d;
  }
  nst = 0;
  for (int T = w; T < 42; T += 4, ++nst) {
    float4v d = ds[nst];
    if (T < 40) {
      float bv = (T < 24) ? bih[T * 16 + jj]
               : (T < 32) ? bg[(T - 24) * 16 + jj] : bgg[(T - 32) * 16 + jj];
      int col = (T < 24) ? (T * 16 + jj) : (384 + (T - 24) * 16 + jj);
#pragma unroll
      for (int r = 0; r < 4; ++r)
        St[(seg * 4 + r) * SS + col] = f2bf(d[r] + bv);
    } else {
#pragma unroll
      for (int r = 0; r < 4; ++r) {
        int tok = seg * 4 + r;
        if (tok < NT)
          wallb[((size_t)(b * TT + t0 + tok)) * 32 + (T - 40) * 16 + jj] = d[r];
      }
    }
  }
  __syncthreads();

  // ---- coalesced copy-out + c1/c2
  {
    const int tok = tid >> 4, sg = tid & 15;
    if (tok < NT) {
      size_t gt = (size_t)b * TT + t0 + tok;
#pragma unroll
      for (int p = 0; p < 3; ++p)
        *(short8v*)(gxb + gt * 384 + sg * 24 + p * 8) = *(short8v*)(St + tok * SS + sg * 24 + p * 8);
#pragma unroll
      for (int p = 0; p < 2; ++p)
        *(short8v*)(xgx + gt * 256 + sg * 16 + p * 8) = *(short8v*)(St + tok * SS + 384 + sg * 16 + p * 8);
    }
  }
  if (tid < 32) {
    int tau = tid & 15, which = tid >> 4;
    if (tau < NT) {
      const ushort* xr = which ? (Yl + tau * XS) : (Xl + tau * XS + 128);
      const float* wv = (which ? Wp1 : Wp) + 256;
      float acc = which ? bp1[0] : bp[0];
      for (int j = 0; j < 128; ++j) acc = fmaf(wv[j], bf2f(xr[j]), acc);
      (which ? c2b : c1b)[b * TT + t0 + tau] = acc;
    }
  }
}

// ---------------------------------------------------------------------------
// Fused scans. LDS-only barriers; dist-2 global prefetch; DPP reductions.
// ---------------------------------------------------------------------------
__global__ __launch_bounds__(512, 2) void scan_k(
    const float* __restrict__ Wf, const float* __restrict__ bf_,
    const float* __restrict__ Wg, const float* __restrict__ Wgg,
    const float* __restrict__ Whh, const float* __restrict__ bhh,
    const float* __restrict__ h0v, const float* __restrict__ m0,
    const ushort* __restrict__ gxb, const ushort* __restrict__ xgx,
    const float* __restrict__ wallb,
    ushort* __restrict__ htsm, ushort* __restrict__ htsg)
{
  const int tid = threadIdx.x;
  const int w = tid >> 6, l = tid & 63, jj = l & 15, seg = l >> 4;

  if (blockIdx.x < 64) {
    // ================= memory scan =================
    const int b = blockIdx.x;
    __shared__ ushort h_bf[32 * 128];
    __shared__ float ht_f[128];
    __shared__ float LGf[128];

    const int o = w * 16 + (l >> 2);   // P1/P2 output row
    const int kc = (l & 3) * 32;       // this lane's k-chunk
    const int lo2 = l & 3;
    const int n0 = w * 16 + seg * 4;   // C-frag columns (MFMA/epilogue)

    // A-frags: WfA rows (uses jj/seg mapping)
    short8v afr[4];
#pragma unroll
    for (int ks = 0; ks < 4; ++ks) {
      const float* src = Wf + (w * 16 + jj) * 256 + ks * 32 + seg * 8;
      short8v tv;
#pragma unroll
      for (int j = 0; j < 8; ++j) tv[j] = (short)f2bf(src[j]);
      afr[ks] = tv;
    }
    // matvec weights (quad-chunk mapping)
    float wgr[32], wggr[32], wfbr[32];
#pragma unroll
    for (int i = 0; i < 32; ++i) {
      wgr[i]  = Wg[o * 256 + kc + i];
      wggr[i] = Wgg[o * 256 + kc + i];
      wfbr[i] = Wf[o * 256 + 128 + kc + i];
    }
    const float bfv = bf_[o];

    // init h = m0
    float hreg[2][4];
#pragma unroll
    for (int nt = 0; nt < 2; ++nt) {
      int k = nt * 16 + jj;
      float4v m = *(const float4v*)(m0 + k * 128 + n0);
#pragma unroll
      for (int r = 0; r < 4; ++r) hreg[nt][r] = m[r];
      int p = ((n0 >> 3) + k) & 15;
      short4v pk;
#pragma unroll
      for (int r = 0; r < 4; ++r) pk[r] = (short)f2bf(hreg[nt][r]);
      *(short4v*)(h_bf + k * 128 + p * 8 + (n0 & 7)) = pk;
    }
    const float* wl = wallb + (size_t)b * TT * 32;
    const ushort* xgp = xgx + (size_t)b * TT * 256;
    float wv0 = wl[jj], wv1 = wl[16 + jj];
    float wn0 = wl[32 + jj], wn1 = wl[48 + jj];
    float xc = (lo2 < 2) ? bf2f(xgp[lo2 * 128 + o]) : 0.f;
    float xn = (lo2 < 2) ? bf2f(xgp[256 + lo2 * 128 + o]) : 0.f;
    // ht0
    {
      float4v htp;
#pragma unroll
      for (int r = 0; r < 4; ++r) {
        htp[r] = rsum16(wv0 * hreg[0][r] + wv1 * hreg[1][r]);
      }
      if (jj == 0) *(float4v*)(ht_f + n0) = htp;
    }
    __syncthreads();

    for (int t = 0; t < TT - 1; ++t) {
      // ---- dist-2 global prefetch (never drained by barriers)
      int tn = (t + 2 < TT - 1) ? (t + 2) : (TT - 2);
      float wf0 = wl[(t + 2 <= TT - 1 ? t + 2 : TT - 1) * 32 + jj];
      float wf1 = wl[(t + 2 <= TT - 1 ? t + 2 : TT - 1) * 32 + 16 + jj];
      float xf = (lo2 < 2) ? bf2f(xgp[(size_t)tn * 256 + lo2 * 128 + o]) : 0.f;

      // ---- MFMA (matrix pipe, off the serial chain)
      float4v acc0 = {0,0,0,0}, acc1 = {0,0,0,0};
#pragma unroll
      for (int ks = 0; ks < 4; ++ks) {
        int g = ks * 4 + seg;
        int p0 = (g + jj) & 15;
        int p1 = (g + 16 + jj) & 15;
        short8v bv0 = *(short8v*)(h_bf + jj * 128 + p0 * 8);
        short8v bv1 = *(short8v*)(h_bf + (16 + jj) * 128 + p1 * 8);
        acc0 = __builtin_amdgcn_mfma_f32_16x16x32_bf16(afr[ks], bv0, acc0, 0, 0, 0);
        acc1 = __builtin_amdgcn_mfma_f32_16x16x32_bf16(afr[ks], bv1, acc1, 0, 0, 0);
      }

      // ---- P1: gain/gate logits, 4 accumulators, quad reduce
      float4v hx[8];
#pragma unroll
      for (int i = 0; i < 8; ++i) hx[i] = *(const float4v*)(ht_f + kc + i * 4);
      float gaA = (lo2 == 0) ? xc : 0.f, gaB = 0.f, gaC = 0.f, gaD = 0.f;
      float gbA = (lo2 == 1) ? xc : 0.f, gbB = 0.f, gbC = 0.f, gbD = 0.f;
#pragma unroll
      for (int i = 0; i < 8; i += 4) {
#pragma unroll
        for (int r = 0; r < 4; ++r) {
          gaA = fmaf(wgr[(i + 0) * 4 + r], hx[i + 0][r], gaA);
          gaB = fmaf(wgr[(i + 1) * 4 + r], hx[i + 1][r], gaB);
          gaC = fmaf(wgr[(i + 2) * 4 + r], hx[i + 2][r], gaC);
          gaD = fmaf(wgr[(i + 3) * 4 + r], hx[i + 3][r], gaD);
          gbA = fmaf(wggr[(i + 0) * 4 + r], hx[i + 0][r], gbA);
          gbB = fmaf(wggr[(i + 1) * 4 + r], hx[i + 1][r], gbB);
          gbC = fmaf(wggr[(i + 2) * 4 + r], hx[i + 2][r], gbC);
          gbD = fmaf(wggr[(i + 3) * 4 + r], hx[i + 3][r], gbD);
        }
      }
      float ga = qsum4((gaA + gaB) + (gaC + gaD));
      float gb = qsum4((gbA + gbB) + (gbC + gbD));
      float LG = tanh_f(ga) * sigm(gb);
      if (lo2 == 0) LGf[o] = LG;
      bar_lds();  // B1

      // ---- P2: lgw matvec + epilogue
      float4v l4[8];
#pragma unroll
      for (int i = 0; i < 8; ++i) l4[i] = *(const float4v*)(LGf + kc + i * 4);
      float laA = 0.f, laB = 0.f, laC = 0.f, laD = 0.f;
#pragma unroll
      for (int i = 0; i < 8; i += 4) {
#pragma unroll
        for (int r = 0; r < 4; ++r) {
          laA = fmaf(wfbr[(i + 0) * 4 + r], l4[i + 0][r], laA);
          laB = fmaf(wfbr[(i + 1) * 4 + r], l4[i + 1][r], laB);
          laC = fmaf(wfbr[(i + 2) * 4 + r], l4[i + 2][r], laC);
          laD = fmaf(wfbr[(i + 3) * 4 + r], l4[i + 3][r], laD);
        }
      }
      float la = qsum4((laA + laB) + (laC + laD)) + bfv;
      float lw[4];
#pragma unroll
      for (int r = 0; r < 4; ++r)
        lw[r] = __shfl(la, seg * 16 + 4 * r, 64);
      float4v lg4 = *(const float4v*)(LGf + n0);

      float4v htp = {0,0,0,0};
#pragma unroll
      for (int nt = 0; nt < 2; ++nt) {
        float wvv = nt ? wv1 : wv0;
        float wnn = nt ? wn1 : wn0;
        float4v a = nt ? acc1 : acc0;
#pragma unroll
        for (int r = 0; r < 4; ++r) {
          float gam = sigm(a[r] + lw[r]);
          float hn = fmaf(gam, hreg[nt][r], wvv * lg4[r]);
          hreg[nt][r] = hn;
          htp[r] = fmaf(wnn, hn, htp[r]);
        }
        int k = nt * 16 + jj;
        int p = ((n0 >> 3) + k) & 15;
        short4v pk;
#pragma unroll
        for (int r = 0; r < 4; ++r) pk[r] = (short)f2bf(hreg[nt][r]);
        *(short4v*)(h_bf + k * 128 + p * 8 + (n0 & 7)) = pk;
      }
#pragma unroll
      for (int r = 0; r < 4; ++r) htp[r] = rsum16(htp[r]);
      if (jj == 0) {
        *(float4v*)(ht_f + n0) = htp;
        short4v hp;
#pragma unroll
        for (int r = 0; r < 4; ++r) hp[r] = (short)f2bf(htp[r]);
        *(short4v*)(htsm + ((size_t)b * TT + t) * 128 + n0) = hp;
      }
      wv0 = wn0; wv1 = wn1; wn0 = wf0; wn1 = wf1; xc = xn; xn = xf;
      bar_lds();  // B2
    }
  } else {
    // ================= GRU =================
    const int b = blockIdx.x - 64;
    __shared__ float gh_l[384];
    __shared__ ushort hbg[128];

    short8v wfr[3][4];
    float4v bfr[3];
#pragma unroll
    for (int i = 0; i < 3; ++i) {
      int Mt = w + i * 8;
#pragma unroll
      for (int ks = 0; ks < 4; ++ks) {
        const float* src = Whh + (Mt * 16 + jj) * 128 + ks * 32 + seg * 8;
        short8v tv;
#pragma unroll
        for (int j = 0; j < 8; ++j) tv[j] = (short)f2bf(src[j]);
        wfr[i][ks] = tv;
      }
      bfr[i] = *(const float4v*)(bhh + Mt * 16 + seg * 4);
    }
    const ushort* gpb = gxb + (size_t)b * TT * 384;
    float hj = 0.f;
    ushort gc0 = 0, gc1 = 0, gc2 = 0, gn0 = 0, gn1 = 0, gn2 = 0;
    if (tid < 128) {
      hj = h0v[tid];
      hbg[tid] = f2bf(hj);
      gc0 = gpb[tid]; gc1 = gpb[128 + tid]; gc2 = gpb[256 + tid];
      gn0 = gpb[384 + tid]; gn1 = gpb[512 + tid]; gn2 = gpb[640 + tid];
    }
    __syncthreads();

    for (int t = 0; t < TT - 1; ++t) {
      ushort gf0 = 0, gf1 = 0, gf2 = 0;
      if (tid < 128) {
        int tf = (t + 2 < TT - 1) ? (t + 2) : (TT - 2);
        const ushort* gp = gpb + (size_t)tf * 384;
        gf0 = gp[tid]; gf1 = gp[128 + tid]; gf2 = gp[256 + tid];
      }
      short8v bfrg[4];
#pragma unroll
      for (int ks = 0; ks < 4; ++ks)
        bfrg[ks] = *(short8v*)(hbg + ks * 32 + seg * 8);
      float4v acc0 = bfr[0], acc1 = bfr[1], acc2 = bfr[2];
#pragma unroll
      for (int ks = 0; ks < 4; ++ks) {
        acc0 = __builtin_amdgcn_mfma_f32_16x16x32_bf16(wfr[0][ks], bfrg[ks], acc0, 0, 0, 0);
        acc1 = __builtin_amdgcn_mfma_f32_16x16x32_bf16(wfr[1][ks], bfrg[ks], acc1, 0, 0, 0);
        acc2 = __builtin_amdgcn_mfma_f32_16x16x32_bf16(wfr[2][ks], bfrg[ks], acc2, 0, 0, 0);
      }
      if (jj == 0) {
        *(float4v*)(gh_l + (w + 0) * 16 + seg * 4) = acc0;
        *(float4v*)(gh_l + (w + 8) * 16 + seg * 4) = acc1;
        *(float4v*)(gh_l + (w + 16) * 16 + seg * 4) = acc2;
      }
      bar_lds();
      if (tid < 128) {
        float r = sigm(bf2f(gc0) + gh_l[tid]);
        float z = sigm(bf2f(gc1) + gh_l[128 + tid]);
        float n = tanh_f(bf2f(gc2) + r * gh_l[256 + tid]);
        hj = fmaf(1.f - z, n, z * hj);
        hbg[tid] = f2bf(hj);
        htsg[((size_t)b * TT + t) * 128 + tid] = f2bf(hj);
      }
      gc0 = gn0; gc1 = gn1; gc2 = gn2;
      gn0 = gf0; gn1 = gf1; gn2 = gf2;
      bar_lds();
    }
  }
}

// ---------------------------------------------------------------------------
__global__ __launch_bounds__(256) void combine_k(
    const ushort* __restrict__ htsg, const ushort* __restrict__ htsm,
    const float* __restrict__ c1b, const float* __restrict__ c2b,
    const float* __restrict__ Wp, const float* __restrict__ Wp1,
    float* __restrict__ out)
{
  const int b = blockIdx.x;
  const int wv = threadIdx.x >> 6;
  const int lane = threadIdx.x & 63;
  const float w0 = Wp[lane], w1 = Wp[64 + lane], w2 = Wp[128 + lane], w3 = Wp[192 + lane];
  const float v0 = Wp1[lane], v1 = Wp1[64 + lane], v2 = Wp1[128 + lane], v3 = Wp1[192 + lane];
  if (threadIdx.x == 0) out[(size_t)b * TT] = 0.f;
  for (int tau = wv; tau < TT - 1; tau += 4) {
    size_t base = ((size_t)b * TT + tau) * 128;
    float hg0 = bf2f(htsg[base + lane]), hg1 = bf2f(htsg[base + 64 + lane]);
    float hm0 = bf2f(htsm[base + lane]), hm1 = bf2f(htsm[base + 64 + lane]);
    float qa = hg0 * w0 + hg1 * w1 + hm0 * w2 + hm1 * w3;
    float qb = hg0 * v0 + hg1 * v1 + hm0 * v2 + hm1 * v3;
#pragma unroll
    for (int m = 1; m < 64; m <<= 1) {
      qa += __shfl_xor(qa, m, 64);
      qb += __shfl_xor(qb, m, 64);
    }
    if (lane == 0) {
      size_t idx = (size_t)b * TT + tau + 1;
      out[idx] = sigm(qa + c1b[idx]) * sigm(qb + c2b[idx]);
    }
  }
}

// ---------------------------------------------------------------------------
extern "C" void kernel_launch(void* const* d_in, const int* in_sizes, int n_in,
                              void* d_out, int out_size, void* d_ws, size_t ws_size,
                              hipStream_t stream) {
  (void)in_sizes; (void)n_in; (void)out_size; (void)ws_size;
  const int* a_data = (const int*)d_in[1];
  const int* e_data = (const int*)d_in[2];
  const float* qm   = (const float*)d_in[4];
  const float* semb = (const float*)d_in[5];
  const float* aemb = (const float*)d_in[6];
  const float* eemb = (const float*)d_in[7];
  const float* W1 = (const float*)d_in[8];   const float* b1 = (const float*)d_in[9];
  const float* W2 = (const float*)d_in[10];  const float* b2 = (const float*)d_in[11];
  const float* W3 = (const float*)d_in[12];  const float* b3 = (const float*)d_in[13];
  const float* key = (const float*)d_in[14];
  const float* Wih = (const float*)d_in[15]; const float* Whh = (const float*)d_in[16];
  const float* bih = (const float*)d_in[17]; const float* bhh = (const float*)d_in[18];
  const float* Wg  = (const float*)d_in[19]; const float* bg  = (const float*)d_in[20];
  const float* Wgg = (const float*)d_in[21]; const float* bgg = (const float*)d_in[22];
  const float* Wf  = (const float*)d_in[23]; const float* bf_ = (const float*)d_in[24];
  const float* Wp  = (const float*)d_in[25]; const float* bp  = (const float*)d_in[26];
  const float* Wp1 = (const float*)d_in[27]; const float* bp1 = (const float*)d_in[28];
  const float* h0v = (const float*)d_in[29]; const float* m0  = (const float*)d_in[30];

  char* ws = (char*)d_ws;
  ushort* gxb  = (ushort*)(ws + 0);
  ushort* xgx  = (ushort*)(ws + 24576000);
  float* wallb = (float*)(ws + 40960000);
  ushort* htsm = (ushort*)(ws + 45056000);
  ushort* htsg = (ushort*)(ws + 53248000);
  float* c1b   = (float*)(ws + 61440000);
  float* c2b   = (float*)(ws + 61568000);
  ushort* wts  = (ushort*)(ws + 61696000);
  float* out = (float*)d_out;

  conv_k<<<dim3(784), dim3(256), 0, stream>>>(W1, W2, W3, Wih, key, Wg, Wgg, wts);
  phase1_k<<<dim3(2048), dim3(256), 0, stream>>>(
      a_data, e_data, qm, semb, aemb, eemb, b1, b2, b3, bih, bg, bgg,
      Wp, bp, Wp1, bp1, wts, gxb, xgx, wallb, c1b, c2b);
  scan_k<<<dim3(128), dim3(512), 0, stream>>>(
      Wf, bf_, Wg, Wgg, Whh, bhh, h0v, m0, gxb, xgx, wallb, htsm, htsg);
  combine_k<<<dim3(64), dim3(256), 0, stream>>>(
      htsg, htsm, c1b, c2b, Wp, Wp1, out);
}

// Round 5
// 1041.896 us; speedup vs baseline: 2.2647x; 1.2243x over previous
//
#include <hip/hip_runtime.h>

#define TT 500
typedef __attribute__((ext_vector_type(8))) short short8v;
typedef __attribute__((ext_vector_type(4))) short short4v;
typedef __attribute__((ext_vector_type(4))) float float4v;
typedef unsigned short ushort;

__device__ __forceinline__ ushort f2bf(float f) {
  union { float f; unsigned u; } v; v.f = f;
  unsigned r = v.u + 0x7FFFu + ((v.u >> 16) & 1u);
  return (ushort)(r >> 16);
}
__device__ __forceinline__ float bf2f(ushort u) {
  union { unsigned u; float f; } v; v.u = ((unsigned)u) << 16;
  return v.f;
}
__device__ __forceinline__ float sigm(float x) {
  return __builtin_amdgcn_rcpf(1.f + __builtin_amdgcn_exp2f(-1.44269504088896341f * x));
}
__device__ __forceinline__ float tanh_f(float x) {
  return 1.f - 2.f * __builtin_amdgcn_rcpf(1.f + __builtin_amdgcn_exp2f(2.88539008177792682f * x));
}
// LDS-only barrier: does NOT drain vmcnt -> global prefetches stay in flight.
__device__ __forceinline__ void bar_lds() {
  asm volatile("s_waitcnt lgkmcnt(0)\ns_barrier" ::: "memory");
}
template <int CTRL>
__device__ __forceinline__ float dppadd(float v) {
  int a = __builtin_amdgcn_update_dpp(0, __builtin_bit_cast(int, v), CTRL, 0xF, 0xF, true);
  return v + __builtin_bit_cast(float, a);
}
__device__ __forceinline__ float rsum16(float v) {  // sum over 16-lane row
  v = dppadd<0xB1>(v);
  v = dppadd<0x4E>(v);
  v = dppadd<0x141>(v);  // row_half_mirror
  v = dppadd<0x140>(v);  // row_mirror
  return v;
}

// ---------------------------------------------------------------------------
// phase0: weights -> bf16
// ---------------------------------------------------------------------------
__global__ __launch_bounds__(256) void conv_k(
    const float* __restrict__ W1, const float* __restrict__ W2,
    const float* __restrict__ W3, const float* __restrict__ Wih,
    const float* __restrict__ key, const float* __restrict__ Wg,
    const float* __restrict__ Wgg, ushort* __restrict__ wts)
{
  int idx = blockIdx.x * 256 + threadIdx.x;
  if (idx >= 200704) return;
  float v;
  if (idx < 32768)       v = W1[idx];
  else if (idx < 81920)  v = W2[idx - 32768];
  else if (idx < 114688) v = W3[idx - 81920];
  else if (idx < 163840) v = Wih[idx - 114688];
  else if (idx < 167936) v = key[idx - 163840];
  else {
    int j = idx - 167936, o = j >> 7, k = j & 127;
    v = (o < 128) ? Wg[o * 256 + 128 + k] : Wgg[(o - 128) * 256 + 128 + k];
  }
  wts[idx] = f2bf(v);
}

// ---------------------------------------------------------------------------
// phase1: token-parallel precompute (MFMA GEMMs + ballot-compressed gather)
// ---------------------------------------------------------------------------
#define XS 424
#define SS 648

__global__ __launch_bounds__(256, 2) void phase1_k(
    const int* __restrict__ a_data, const int* __restrict__ e_data,
    const float* __restrict__ qm, const float* __restrict__ semb,
    const float* __restrict__ aemb, const float* __restrict__ eemb,
    const float* __restrict__ b1, const float* __restrict__ b2,
    const float* __restrict__ b3, const float* __restrict__ bih,
    const float* __restrict__ bg, const float* __restrict__ bgg,
    const float* __restrict__ Wp, const float* __restrict__ bp,
    const float* __restrict__ Wp1, const float* __restrict__ bp1,
    const ushort* __restrict__ wts,
    ushort* __restrict__ gxb, ushort* __restrict__ xgx,
    float* __restrict__ wallb, float* __restrict__ c1b, float* __restrict__ c2b)
{
  __shared__ ushort Xl[16 * XS];
  __shared__ ushort Yl[16 * XS];
  __shared__ ushort St[16 * SS];
  const int tid = threadIdx.x;
  const int b = blockIdx.x >> 5, chunk = blockIdx.x & 31;
  const int t0 = chunk * 16;
  const int NT = (TT - t0 < 16) ? (TT - t0) : 16;
  const ushort* w1b  = wts;
  const ushort* w2b  = wts + 32768;
  const ushort* w3b  = wts + 81920;
  const ushort* wihb = wts + 114688;
  const ushort* keyb = wts + 163840;
  const ushort* wgb  = wts + 167936;

  // ---- stage 0: X via ballot-compressed sparse gather
  {
    const int tok = tid >> 4, l16 = tid & 15;
    const int tsrc = (tok < NT) ? tok : (NT - 1);
    const int gt = b * TT + t0 + tsrc;
    const int e = e_data[gt], a = a_data[gt];
    const float* qrow = qm + (size_t)e * 101;
    float qv[7];
#pragma unroll
    for (int i = 0; i < 7; ++i) {
      int s = l16 + 16 * i;
      qv[i] = (s < 101) ? qrow[s] : 0.f;
    }
    const float* sbase = semb + l16 * 8;
    float4v acc0 = {0,0,0,0}, acc1 = {0,0,0,0};
    float cnt = 0.f;
#pragma unroll
    for (int i = 0; i < 7; ++i) {
      unsigned long long bal = __ballot(qv[i] != 0.f);
      unsigned m = (unsigned)((bal >> (tid & 48)) & 0xFFFFull);
      cnt += (float)__popc(m);
      while (m) {
        int s = 16 * i + __builtin_ctz(m);
        m &= m - 1;
        acc0 += *(const float4v*)(sbase + s * 128);
        acc1 += *(const float4v*)(sbase + s * 128 + 4);
      }
    }
    float inv = 1.f / fmaxf(cnt, 1.f);
    ushort* xr = Xl + tok * XS + l16 * 8;
#pragma unroll
    for (int r = 0; r < 4; ++r) { xr[r] = f2bf(acc0[r] * inv); xr[4 + r] = f2bf(acc1[r] * inv); }
    const float* ee = eemb + (size_t)e * 128 + l16 * 8;
    const float* ae = aemb + a * 128 + l16 * 8;
    ushort* xe = Xl + tok * XS + 128 + l16 * 8;
    ushort* xa = Xl + tok * XS + 256 + l16 * 8;
#pragma unroll
    for (int r = 0; r < 8; ++r) { xe[r] = f2bf(ee[r]); xa[r] = f2bf(ae[r]); }
  }
  __syncthreads();

  const int w = tid >> 6, l = tid & 63, jj = l & 15, seg = l >> 4;

  // ---- stage A: Y via MFMA
  short8v ax[12];
#pragma unroll
  for (int i = 0; i < 12; ++i)
    ax[i] = *(short8v*)(Xl + jj * XS + i * 32 + seg * 8);

  for (int T = w; T < 24; T += 4) {
    float4v d = {0,0,0,0};
    float bv;
    if (T < 8) {
      const ushort* Bp = w1b + (T * 16 + jj) * 256 + seg * 8;
      bv = b1[T * 16 + jj];
#pragma unroll
      for (int k = 0; k < 8; ++k)
        d = __builtin_amdgcn_mfma_f32_16x16x32_bf16(ax[k], *(const short8v*)(Bp + k * 32), d, 0, 0, 0);
    } else if (T < 16) {
      const ushort* Bp = w2b + ((T - 8) * 16 + jj) * 384 + seg * 8;
      bv = b2[(T - 8) * 16 + jj];
#pragma unroll
      for (int k = 0; k < 12; ++k)
        d = __builtin_amdgcn_mfma_f32_16x16x32_bf16(ax[k], *(const short8v*)(Bp + k * 32), d, 0, 0, 0);
    } else {
      const ushort* Bp = w3b + ((T - 16) * 16 + jj) * 256 + seg * 8;
      bv = b3[(T - 16) * 16 + jj];
#pragma unroll
      for (int k = 0; k < 8; ++k)
        d = __builtin_amdgcn_mfma_f32_16x16x32_bf16(ax[4 + k], *(const short8v*)(Bp + k * 32), d, 0, 0, 0);
    }
#pragma unroll
    for (int r = 0; r < 4; ++r) {
      float y = d[r] + bv;
      Yl[(seg * 4 + r) * XS + T * 16 + jj] = f2bf(y > 0.f ? y : 0.f);
    }
  }
  __syncthreads();

  // ---- stage B: gx / xgx / wall
  short8v ay[12];
#pragma unroll
  for (int i = 0; i < 12; ++i)
    ay[i] = *(short8v*)(Yl + jj * XS + i * 32 + seg * 8);

  float4v ds[11];
  int nst = 0;
  for (int T = w; T < 42; T += 4, ++nst) {
    const ushort* Bp; int ai;
    if (T < 24)      { Bp = wihb + (T * 16 + jj) * 128 + seg * 8;        ai = 8; }
    else if (T < 40) { Bp = wgb  + ((T - 24) * 16 + jj) * 128 + seg * 8; ai = 4; }
    else             { Bp = keyb + ((T - 40) * 16 + jj) * 128 + seg * 8; ai = 0; }
    float4v d = {0,0,0,0};
#pragma unroll
    for (int k = 0; k < 4; ++k)
      d = __builtin_amdgcn_mfma_f32_16x16x32_bf16(ay[ai + k], *(const short8v*)(Bp + k * 32), d, 0, 0, 0);
    ds[nst] = d;
  }
  nst = 0;
  for (int T = w; T < 42; T += 4, ++nst) {
    float4v d = ds[nst];
    if (T < 40) {
      float bv = (T < 24) ? bih[T * 16 + jj]
               : (T < 32) ? bg[(T - 24) * 16 + jj] : bgg[(T - 32) * 16 + jj];
      int col = (T < 24) ? (T * 16 + jj) : (384 + (T - 24) * 16 + jj);
#pragma unroll
      for (int r = 0; r < 4; ++r)
        St[(seg * 4 + r) * SS + col] = f2bf(d[r] + bv);
    } else {
#pragma unroll
      for (int r = 0; r < 4; ++r) {
        int tok = seg * 4 + r;
        if (tok < NT)
          wallb[((size_t)(b * TT + t0 + tok)) * 32 + (T - 40) * 16 + jj] = d[r];
      }
    }
  }
  __syncthreads();

  // ---- coalesced copy-out + c1/c2
  {
    const int tok = tid >> 4, sg = tid & 15;
    if (tok < NT) {
      size_t gt = (size_t)b * TT + t0 + tok;
#pragma unroll
      for (int p = 0; p < 3; ++p)
        *(short8v*)(gxb + gt * 384 + sg * 24 + p * 8) = *(short8v*)(St + tok * SS + sg * 24 + p * 8);
#pragma unroll
      for (int p = 0; p < 2; ++p)
        *(short8v*)(xgx + gt * 256 + sg * 16 + p * 8) = *(short8v*)(St + tok * SS + 384 + sg * 16 + p * 8);
    }
  }
  if (tid < 32) {
    int tau = tid & 15, which = tid >> 4;
    if (tau < NT) {
      const ushort* xr = which ? (Yl + tau * XS) : (Xl + tau * XS + 128);
      const float* wv = (which ? Wp1 : Wp) + 256;
      float acc = which ? bp1[0] : bp[0];
      for (int j = 0; j < 128; ++j) acc = fmaf(wv[j], bf2f(xr[j]), acc);
      (which ? c2b : c1b)[b * TT + t0 + tau] = acc;
    }
  }
}

// ---------------------------------------------------------------------------
// Fused scans. All matvecs on the matrix pipe; D-layout == consumer layout.
// ---------------------------------------------------------------------------
__global__ __launch_bounds__(512) void scan_k(
    const float* __restrict__ Wf, const float* __restrict__ bf_,
    const float* __restrict__ Wg, const float* __restrict__ Wgg,
    const float* __restrict__ Whh, const float* __restrict__ bhh,
    const float* __restrict__ h0v, const float* __restrict__ m0,
    const ushort* __restrict__ gxb, const ushort* __restrict__ xgx,
    const float* __restrict__ wallb,
    ushort* __restrict__ htsm, ushort* __restrict__ htsg)
{
  const int tid = threadIdx.x;
  const int w = tid >> 6, l = tid & 63, jj = l & 15, seg = l >> 4;

  if (blockIdx.x < 64) {
    // ================= memory scan =================
    const int b = blockIdx.x;
    __shared__ __align__(16) ushort h_bf[32 * 128];  // bf16 h_pre, 16B-rot swizzle
    __shared__ __align__(16) ushort htb[128];        // bf16 ht (B-frag broadcast)
    __shared__ __align__(16) ushort LGb[128];        // bf16 LG (B-frag broadcast)

    const int n0 = w * 16 + seg * 4;   // this lane's 4 output rows / C-frag cols

    // A-frags (bf16, one-time convert from fp32 globals):
    short8v afrA[4];   // WfA rows (bigC)
    short8v aggA[4];   // Wg  ht-side rows
    short8v aggB[4];   // Wgg ht-side rows
    short8v alg[4];    // WfB rows (lgw)
#pragma unroll
    for (int ks = 0; ks < 4; ++ks) {
      const float* sA = Wf  + (w * 16 + jj) * 256 + ks * 32 + seg * 8;
      const float* sB = Wg  + (w * 16 + jj) * 256 + ks * 32 + seg * 8;
      const float* sC = Wgg + (w * 16 + jj) * 256 + ks * 32 + seg * 8;
      const float* sD = Wf  + (w * 16 + jj) * 256 + 128 + ks * 32 + seg * 8;
      short8v a, bb, c, d;
#pragma unroll
      for (int j = 0; j < 8; ++j) {
        a[j] = (short)f2bf(sA[j]); bb[j] = (short)f2bf(sB[j]);
        c[j] = (short)f2bf(sC[j]); d[j] = (short)f2bf(sD[j]);
      }
      afrA[ks] = a; aggA[ks] = bb; aggB[ks] = c; alg[ks] = d;
    }
    const float4v bf4 = *(const float4v*)(bf_ + n0);

    // init h = m0
    float hreg[2][4];
#pragma unroll
    for (int nt = 0; nt < 2; ++nt) {
      int k = nt * 16 + jj;
      float4v m = *(const float4v*)(m0 + k * 128 + n0);
#pragma unroll
      for (int r = 0; r < 4; ++r) hreg[nt][r] = m[r];
      int p = ((n0 >> 3) + k) & 15;
      short4v pk;
#pragma unroll
      for (int r = 0; r < 4; ++r) pk[r] = (short)f2bf(hreg[nt][r]);
      *(short4v*)(h_bf + k * 128 + p * 8 + (n0 & 7)) = pk;
    }
    const float* wl = wallb + (size_t)b * TT * 32;
    const ushort* xgp = xgx + (size_t)b * TT * 256;
    float wv0 = wl[jj], wv1 = wl[16 + jj];       // w_0  (k = jj / 16+jj)
    float wn0 = wl[32 + jj], wn1 = wl[48 + jj];  // w_1
    short4v xcg  = *(const short4v*)(xgp + n0);          // xg gain  t=0
    short4v xcgg = *(const short4v*)(xgp + 128 + n0);    // xg gate  t=0
    short4v xng  = *(const short4v*)(xgp + 256 + n0);    // t=1
    short4v xngg = *(const short4v*)(xgp + 384 + n0);
    // ht0 = sum_k w0[k] m0[k]
    {
      float4v htp;
#pragma unroll
      for (int r = 0; r < 4; ++r)
        htp[r] = rsum16(wv0 * hreg[0][r] + wv1 * hreg[1][r]);
      if (jj == 0) {
        short4v hp;
#pragma unroll
        for (int r = 0; r < 4; ++r) hp[r] = (short)f2bf(htp[r]);
        *(short4v*)(htb + n0) = hp;
      }
    }
    __syncthreads();

    for (int t = 0; t < TT - 1; ++t) {
      // ---- dist-2 global prefetch (never drained by LDS barriers)
      int tw = (t + 2 <= TT - 1) ? (t + 2) : (TT - 1);
      float wf0 = wl[tw * 32 + jj], wf1 = wl[tw * 32 + 16 + jj];
      short4v xfg  = *(const short4v*)(xgp + (size_t)tw * 256 + n0);
      short4v xfgg = *(const short4v*)(xgp + (size_t)tw * 256 + 128 + n0);

      // ---- MFMA: bigC[n][k_slot] (matrix pipe)
      float4v acc0 = {0,0,0,0}, acc1 = {0,0,0,0};
#pragma unroll
      for (int ks = 0; ks < 4; ++ks) {
        int g = ks * 4 + seg;
        int p0 = (g + jj) & 15;
        int p1 = (g + 16 + jj) & 15;
        short8v bv0 = *(short8v*)(h_bf + jj * 128 + p0 * 8);
        short8v bv1 = *(short8v*)(h_bf + (16 + jj) * 128 + p1 * 8);
        acc0 = __builtin_amdgcn_mfma_f32_16x16x32_bf16(afrA[ks], bv0, acc0, 0, 0, 0);
        acc1 = __builtin_amdgcn_mfma_f32_16x16x32_bf16(afrA[ks], bv1, acc1, 0, 0, 0);
      }

      // ---- MFMA: u_g/u_gg = [Wg;Wgg]·ht (broadcast B)  -> rows n0+r local
      float4v dg = {0,0,0,0}, dgg = {0,0,0,0};
#pragma unroll
      for (int ks = 0; ks < 4; ++ks) {
        short8v bht = *(short8v*)(htb + ks * 32 + seg * 8);
        dg  = __builtin_amdgcn_mfma_f32_16x16x32_bf16(aggA[ks], bht, dg, 0, 0, 0);
        dgg = __builtin_amdgcn_mfma_f32_16x16x32_bf16(aggB[ks], bht, dgg, 0, 0, 0);
      }
      float lgv[4];
#pragma unroll
      for (int r = 0; r < 4; ++r) {
        float ug  = dg[r]  + bf2f((ushort)xcg[r]);
        float ugg = dgg[r] + bf2f((ushort)xcgg[r]);
        lgv[r] = tanh_f(ug) * sigm(ugg);
      }
      if (jj == 0) {
        short4v lp;
#pragma unroll
        for (int r = 0; r < 4; ++r) lp[r] = (short)f2bf(lgv[r]);
        *(short4v*)(LGb + n0) = lp;
      }
      bar_lds();  // B1

      // ---- MFMA: lgw = WfB·LG (broadcast B) -> rows n0+r local
      float4v dlw = {0,0,0,0};
#pragma unroll
      for (int ks = 0; ks < 4; ++ks) {
        short8v blg = *(short8v*)(LGb + ks * 32 + seg * 8);
        dlw = __builtin_amdgcn_mfma_f32_16x16x32_bf16(alg[ks], blg, dlw, 0, 0, 0);
      }
      float lw[4];
#pragma unroll
      for (int r = 0; r < 4; ++r) lw[r] = dlw[r] + bf4[r];

      // ---- epilogue
      float4v htp = {0,0,0,0};
#pragma unroll
      for (int nt = 0; nt < 2; ++nt) {
        float wvv = nt ? wv1 : wv0;
        float wnn = nt ? wn1 : wn0;
        float4v a = nt ? acc1 : acc0;
#pragma unroll
        for (int r = 0; r < 4; ++r) {
          float gam = sigm(a[r] + lw[r]);
          float hn = fmaf(gam, hreg[nt][r], wvv * lgv[r]);
          hreg[nt][r] = hn;
          htp[r] = fmaf(wnn, hn, htp[r]);
        }
        int k = nt * 16 + jj;
        int p = ((n0 >> 3) + k) & 15;
        short4v pk;
#pragma unroll
        for (int r = 0; r < 4; ++r) pk[r] = (short)f2bf(hreg[nt][r]);
        *(short4v*)(h_bf + k * 128 + p * 8 + (n0 & 7)) = pk;
      }
#pragma unroll
      for (int r = 0; r < 4; ++r) htp[r] = rsum16(htp[r]);
      if (jj == 0) {
        short4v hp;
#pragma unroll
        for (int r = 0; r < 4; ++r) hp[r] = (short)f2bf(htp[r]);
        *(short4v*)(htb + n0) = hp;
        *(short4v*)(htsm + ((size_t)b * TT + t) * 128 + n0) = hp;
      }
      wv0 = wn0; wv1 = wn1; wn0 = wf0; wn1 = wf1;
      xcg = xng; xcgg = xngg; xng = xfg; xngg = xfgg;
      bar_lds();  // B2
    }
  } else {
    // ================= GRU =================
    const int b = blockIdx.x - 64;
    __shared__ float gh_l[384];
    __shared__ __align__(16) ushort hbg[128];

    short8v wfr[3][4];
    float4v bfr[3];
#pragma unroll
    for (int i = 0; i < 3; ++i) {
      int Mt = w + i * 8;
#pragma unroll
      for (int ks = 0; ks < 4; ++ks) {
        const float* src = Whh + (Mt * 16 + jj) * 128 + ks * 32 + seg * 8;
        short8v tv;
#pragma unroll
      for (int j = 0; j < 8; ++j) tv[j] = (short)f2bf(src[j]);
        wfr[i][ks] = tv;
      }
      bfr[i] = *(const float4v*)(bhh + Mt * 16 + seg * 4);
    }
    const ushort* gpb = gxb + (size_t)b * TT * 384;
    float hj = 0.f;
    ushort gc0 = 0, gc1 = 0, gc2 = 0, gn0 = 0, gn1 = 0, gn2 = 0;
    if (tid < 128) {
      hj = h0v[tid];
      hbg[tid] = f2bf(hj);
      gc0 = gpb[tid]; gc1 = gpb[128 + tid]; gc2 = gpb[256 + tid];
      gn0 = gpb[384 + tid]; gn1 = gpb[512 + tid]; gn2 = gpb[640 + tid];
    }
    __syncthreads();

    for (int t = 0; t < TT - 1; ++t) {
      ushort gf0 = 0, gf1 = 0, gf2 = 0;
      if (tid < 128) {
        int tf = (t + 2 < TT - 1) ? (t + 2) : (TT - 2);
        const ushort* gp = gpb + (size_t)tf * 384;
        gf0 = gp[tid]; gf1 = gp[128 + tid]; gf2 = gp[256 + tid];
      }
      short8v bfrg[4];
#pragma unroll
      for (int ks = 0; ks < 4; ++ks)
        bfrg[ks] = *(short8v*)(hbg + ks * 32 + seg * 8);
      float4v acc0 = bfr[0], acc1 = bfr[1], acc2 = bfr[2];
#pragma unroll
      for (int ks = 0; ks < 4; ++ks) {
        acc0 = __builtin_amdgcn_mfma_f32_16x16x32_bf16(wfr[0][ks], bfrg[ks], acc0, 0, 0, 0);
        acc1 = __builtin_amdgcn_mfma_f32_16x16x32_bf16(wfr[1][ks], bfrg[ks], acc1, 0, 0, 0);
        acc2 = __builtin_amdgcn_mfma_f32_16x16x32_bf16(wfr[2][ks], bfrg[ks], acc2, 0, 0, 0);
      }
      if (jj == 0) {
        *(float4v*)(gh_l + (w + 0) * 16 + seg * 4) = acc0;
        *(float4v*)(gh_l + (w + 8) * 16 + seg * 4) = acc1;
        *(float4v*)(gh_l + (w + 16) * 16 + seg * 4) = acc2;
      }
      bar_lds();
      if (tid < 128) {
        float r = sigm(bf2f(gc0) + gh_l[tid]);
        float z = sigm(bf2f(gc1) + gh_l[128 + tid]);
        float n = tanh_f(bf2f(gc2) + r * gh_l[256 + tid]);
        hj = fmaf(1.f - z, n, z * hj);
        hbg[tid] = f2bf(hj);
        htsg[((size_t)b * TT + t) * 128 + tid] = f2bf(hj);
      }
      gc0 = gn0; gc1 = gn1; gc2 = gn2;
      gn0 = gf0; gn1 = gf1; gn2 = gf2;
      bar_lds();
    }
  }
}

// ---------------------------------------------------------------------------
__global__ __launch_bounds__(256) void combine_k(
    const ushort* __restrict__ htsg, const ushort* __restrict__ htsm,
    const float* __restrict__ c1b, const float* __restrict__ c2b,
    const float* __restrict__ Wp, const float* __restrict__ Wp1,
    float* __restrict__ out)
{
  const int b = blockIdx.x;
  const int wv = threadIdx.x >> 6;
  const int lane = threadIdx.x & 63;
  const float w0 = Wp[lane], w1 = Wp[64 + lane], w2 = Wp[128 + lane], w3 = Wp[192 + lane];
  const float v0 = Wp1[lane], v1 = Wp1[64 + lane], v2 = Wp1[128 + lane], v3 = Wp1[192 + lane];
  if (threadIdx.x == 0) out[(size_t)b * TT] = 0.f;
  for (int tau = wv; tau < TT - 1; tau += 4) {
    size_t base = ((size_t)b * TT + tau) * 128;
    float hg0 = bf2f(htsg[base + lane]), hg1 = bf2f(htsg[base + 64 + lane]);
    float hm0 = bf2f(htsm[base + lane]), hm1 = bf2f(htsm[base + 64 + lane]);
    float qa = hg0 * w0 + hg1 * w1 + hm0 * w2 + hm1 * w3;
    float qb = hg0 * v0 + hg1 * v1 + hm0 * v2 + hm1 * v3;
#pragma unroll
    for (int m = 1; m < 64; m <<= 1) {
      qa += __shfl_xor(qa, m, 64);
      qb += __shfl_xor(qb, m, 64);
    }
    if (lane == 0) {
      size_t idx = (size_t)b * TT + tau + 1;
      out[idx] = sigm(qa + c1b[idx]) * sigm(qb + c2b[idx]);
    }
  }
}

// ---------------------------------------------------------------------------
extern "C" void kernel_launch(void* const* d_in, const int* in_sizes, int n_in,
                              void* d_out, int out_size, void* d_ws, size_t ws_size,
                              hipStream_t stream) {
  (void)in_sizes; (void)n_in; (void)out_size; (void)ws_size;
  const int* a_data = (const int*)d_in[1];
  const int* e_data = (const int*)d_in[2];
  const float* qm   = (const float*)d_in[4];
  const float* semb = (const float*)d_in[5];
  const float* aemb = (const float*)d_in[6];
  const float* eemb = (const float*)d_in[7];
  const float* W1 = (const float*)d_in[8];   const float* b1 = (const float*)d_in[9];
  const float* W2 = (const float*)d_in[10];  const float* b2 = (const float*)d_in[11];
  const float* W3 = (const float*)d_in[12];  const float* b3 = (const float*)d_in[13];
  const float* key = (const float*)d_in[14];
  const float* Wih = (const float*)d_in[15]; const float* Whh = (const float*)d_in[16];
  const float* bih = (const float*)d_in[17]; const float* bhh = (const float*)d_in[18];
  const float* Wg  = (const float*)d_in[19]; const float* bg  = (const float*)d_in[20];
  const float* Wgg = (const float*)d_in[21]; const float* bgg = (const float*)d_in[22];
  const float* Wf  = (const float*)d_in[23]; const float* bf_ = (const float*)d_in[24];
  const float* Wp  = (const float*)d_in[25]; const float* bp  = (const float*)d_in[26];
  const float* Wp1 = (const float*)d_in[27]; const float* bp1 = (const float*)d_in[28];
  const float* h0v = (const float*)d_in[29]; const float* m0  = (const float*)d_in[30];

  char* ws = (char*)d_ws;
  ushort* gxb  = (ushort*)(ws + 0);
  ushort* xgx  = (ushort*)(ws + 24576000);
  float* wallb = (float*)(ws + 40960000);
  ushort* htsm = (ushort*)(ws + 45056000);
  ushort* htsg = (ushort*)(ws + 53248000);
  float* c1b   = (float*)(ws + 61440000);
  float* c2b   = (float*)(ws + 61568000);
  ushort* wts  = (ushort*)(ws + 61696000);
  float* out = (float*)d_out;

  conv_k<<<dim3(784), dim3(256), 0, stream>>>(W1, W2, W3, Wih, key, Wg, Wgg, wts);
  phase1_k<<<dim3(2048), dim3(256), 0, stream>>>(
      a_data, e_data, qm, semb, aemb, eemb, b1, b2, b3, bih, bg, bgg,
      Wp, bp, Wp1, bp1, wts, gxb, xgx, wallb, c1b, c2b);
  scan_k<<<dim3(128), dim3(512), 0, stream>>>(
      Wf, bf_, Wg, Wgg, Whh, bhh, h0v, m0, gxb, xgx, wallb, htsm, htsg);
  combine_k<<<dim3(64), dim3(256), 0, stream>>>(
      htsg, htsm, c1b, c2b, Wp, Wp1, out);
}